// Round 1
// baseline (488.263 us; speedup 1.0000x reference)
//
#include <hip/hip_runtime.h>

#define NGRID 70144
#define NV 128
#define JT 16

__device__ __forceinline__ float4 f4add(float4 a, float4 b){ return make_float4(a.x+b.x, a.y+b.y, a.z+b.z, a.w+b.w); }
__device__ __forceinline__ float4 f4sub(float4 a, float4 b){ return make_float4(a.x-b.x, a.y-b.y, a.z-b.z, a.w-b.w); }

// Offset (in float2 entries) of ring i's twiddle table: sum_{k<i} m_hi(k) * (nlon(k)/2 + 1)
__device__ __forceinline__ long twoff_of(int i){
  long off = 0;
  for(int k=0;k<i;k++){
    int mh = (5+k < 128) ? (5+k) : 128;
    off += (long)mh * (long)(11 + 2*k);
  }
  return off;
}

// tw[m][j] = (cos(2*pi*m*j/N)/N, -sin(2*pi*m*j/N)/N), j = 0..N/2 (folded)
__global__ void fill_tw(float* __restrict__ tw){
  int ring = blockIdx.x, mc = blockIdx.y;
  int N = 20 + 4*ring, H = N/2;
  int mhi = (5+ring < 128) ? (5+ring) : 128;
  int m0 = mc*32;
  if(m0 >= mhi) return;
  int m1 = (m0+32 < mhi) ? (m0+32) : mhi;
  long base = twoff_of(ring);
  int tot = (m1-m0)*(H+1);
  double invN = 1.0 / (double)N;
  for(int idx = threadIdx.x; idx < tot; idx += blockDim.x){
    int m = m0 + idx/(H+1);
    int j = idx % (H+1);
    int p = (m*j) % N;                    // exact integer phase
    double th = 6.283185307179586477 * (double)p * invN;
    double sn, cs;
    sincos(th, &sn, &cs);
    long o = (base + (long)(m)*(H+1) + j)*2;
    tw[o]   = (float)(cs * invN);
    tw[o+1] = (float)(-sn * invN);
  }
}

// Folded DFT: per (ring, m-tile of 32, batch) block.
// Produces G[s][m][n=ring][b][v][ri] for m in tile (m < m_hi(ring)).
__global__ __launch_bounds__(256) void dft_fold(const float* __restrict__ x,
                                                const float* __restrict__ tw,
                                                float* __restrict__ G){
  int ring = blockIdx.x, mt = blockIdx.y, b = blockIdx.z;
  int N = 20 + 4*ring, H = N/2, JC = H+1;
  int mhi = (5+ring < 128) ? (5+ring) : 128;
  int mbase = mt*32;
  if(mbase >= mhi) return;

  __shared__ __align__(16) float cS[JT][NV], sS[JT][NV], cA[JT][NV], sA[JT][NV];
  __shared__ __align__(16) float twl[JT*32*2];

  int tid = threadIdx.x;
  int v = tid & 127, half = tid >> 7;
  long twbase = twoff_of(ring);
  long offN = (long)ring*(2*ring+18);          // CUMS[ring]
  long a = ring+1;
  long offS = (long)NGRID - a*(2*a+18);        // CUMS[255-ring]
  const float* xn = x + ((long)b*NGRID + offN)*NV;
  const float* xs = x + ((long)b*NGRID + offS)*NV;

  float aSR[16], aSI[16], aAR[16], aAI[16];
  #pragma unroll
  for(int k=0;k<16;k++){ aSR[k]=0.f; aSI[k]=0.f; aAR[k]=0.f; aAI[k]=0.f; }

  for(int j0=0; j0<JC; j0+=JT){
    __syncthreads();
    // stage folded x tiles: c/s (longitude fold) x sym/anti (hemisphere fold)
    for(int idx=tid; idx<JT*32; idx+=256){
      int jj = idx >> 5;
      int v4 = (idx & 31) << 2;
      int j = j0 + jj;
      float4 z = make_float4(0.f,0.f,0.f,0.f);
      float4 nj=z, sj=z, np=z, sp=z;
      if(j < JC){
        nj = *(const float4*)&xn[(long)j*NV + v4];
        sj = *(const float4*)&xs[(long)j*NV + v4];
        if(j > 0 && j < H){
          int jp = N - j;
          np = *(const float4*)&xn[(long)jp*NV + v4];
          sp = *(const float4*)&xs[(long)jp*NV + v4];
        }
      }
      float4 e  = f4add(nj, sj);   // hemi-sum  at j
      float4 o  = f4sub(nj, sj);   // hemi-diff at j
      float4 ep = f4add(np, sp);   // hemi-sum  at N-j (0 at edges)
      float4 op = f4sub(np, sp);
      *(float4*)&cS[jj][v4] = f4add(e, ep);
      *(float4*)&sS[jj][v4] = f4sub(e, ep);
      *(float4*)&cA[jj][v4] = f4add(o, op);
      *(float4*)&sA[jj][v4] = f4sub(o, op);
    }
    // stage twiddles: twl[jj][m_loc] as float2 (clamped so reads stay in-table)
    for(int idx=tid; idx<JT*32; idx+=256){
      int jj = idx >> 5;
      int mm = idx & 31;
      int msrc = mbase + mm; if(msrc > mhi-1) msrc = mhi-1;
      int jsrc = j0 + jj;    if(jsrc > H)     jsrc = H;
      const float2 t = *(const float2*)&tw[(twbase + (long)msrc*JC + jsrc)*2];
      *(float2*)&twl[(jj*32 + mm)*2] = t;
    }
    __syncthreads();
    int jlim = JC - j0; if(jlim > JT) jlim = JT;
    for(int jj=0; jj<jlim; jj++){
      float c_s = cS[jj][v], s_s = sS[jj][v], c_a = cA[jj][v], s_a = sA[jj][v];
      const float* twrow = &twl[(jj*32 + half*16)*2];
      #pragma unroll
      for(int k2=0; k2<8; k2++){
        float4 t4 = *(const float4*)&twrow[k2*4];   // (cos,-sin) for m_loc, m_loc+1
        aSR[2*k2]   += c_s*t4.x;  aSI[2*k2]   += s_s*t4.y;
        aAR[2*k2]   += c_a*t4.x;  aAI[2*k2]   += s_a*t4.y;
        aSR[2*k2+1] += c_s*t4.z;  aSI[2*k2+1] += s_s*t4.w;
        aAR[2*k2+1] += c_a*t4.z;  aAI[2*k2+1] += s_a*t4.w;
      }
    }
  }
  // write G: [s][m][n][b][v][ri]
  long gb_common = (long)ring*1024 + (long)b*256 + (long)v*2;
  #pragma unroll
  for(int k=0;k<16;k++){
    int m = mbase + half*16 + k;
    if(m < mhi){
      long o = (long)m*131072 + gb_common;
      *(float2*)&G[o]             = make_float2(aSR[k], aSI[k]);
      *(float2*)&G[o + 16777216L] = make_float2(aAR[k], aAI[k]);
    }
  }
}

// Per-(m, b, s) Legendre matmul: out[l][v][ri] = sum_{n>=n0} W[m][l][n] * G[n][v][ri]
__global__ __launch_bounds__(256) void legendre_mm(const float* __restrict__ Wsym,
                                                   const float* __restrict__ Want,
                                                   const float* __restrict__ G,
                                                   float* __restrict__ out){
  int m = blockIdx.x, b = blockIdx.y, s = blockIdx.z;
  const float* W = s ? Want : Wsym;             // [128][64][128]
  __shared__ __align__(16) float Wt[128][68];   // transposed [n][l], padded
  int tid = threadIdx.x;
  const float* Wm = W + (long)m*8192;
  for(int idx=tid; idx<8192; idx+=256){
    int l = idx >> 7, n = idx & 127;
    Wt[n][l] = Wm[idx];
  }
  __syncthreads();
  int v = tid & 127, lh = tid >> 7;
  int n0 = (m-4 > 0) ? (m-4) : 0;               // W[m][l][n]==0 for n<m-4 (mask)
  const float* Gs = G + (long)s*16777216 + (long)m*131072 + (long)b*256 + (long)v*2;
  float aR[32], aI[32];
  #pragma unroll
  for(int q=0;q<32;q++){ aR[q]=0.f; aI[q]=0.f; }
  for(int n=n0; n<128; n++){
    float2 g = *(const float2*)&Gs[(long)n*1024];
    const float* wrow = &Wt[n][lh*32];
    #pragma unroll
    for(int q2=0; q2<8; q2++){
      float4 w = *(const float4*)&wrow[q2*4];
      aR[q2*4+0] += w.x*g.x; aI[q2*4+0] += w.x*g.y;
      aR[q2*4+1] += w.y*g.x; aI[q2*4+1] += w.y*g.y;
      aR[q2*4+2] += w.z*g.x; aI[q2*4+2] += w.z*g.y;
      aR[q2*4+3] += w.w*g.x; aI[q2*4+3] += w.w*g.y;
    }
  }
  #pragma unroll
  for(int q=0;q<32;q++){
    int l = lh*32 + q;
    int lf = 2*l + s;                           // interleave sym/anti rows
    long o = (((long)b*128 + lf)*128 + m)*256 + (long)v*2;
    *(float2*)&out[o] = make_float2(aR[q], aI[q]);
  }
}

extern "C" void kernel_launch(void* const* d_in, const int* in_sizes, int n_in,
                              void* d_out, int out_size, void* d_ws, size_t ws_size,
                              hipStream_t stream) {
  const float* x    = (const float*)d_in[0];
  const float* Wsym = (const float*)d_in[1];
  const float* Want = (const float*)d_in[2];
  float* out = (float*)d_out;
  float* ws  = (float*)d_ws;

  // twiddle table size (float2 entries) and aligned G base (floats)
  long two = 0;
  for(int k=0;k<128;k++){ int mh = (5+k<128)?(5+k):128; two += (long)mh*(long)(11+2*k); }
  long GBASE = (two*2 + 255) & ~255L;           // ~12.5 MB tw + 134 MB G in ws

  float* tw = ws;
  float* G  = ws + GBASE;

  hipLaunchKernelGGL(fill_tw,     dim3(128,4),   dim3(256), 0, stream, tw);
  hipLaunchKernelGGL(dft_fold,    dim3(128,4,4), dim3(256), 0, stream, x, tw, G);
  hipLaunchKernelGGL(legendre_mm, dim3(128,4,2), dim3(256), 0, stream, Wsym, Want, G, out);
}

// Round 2
// 428.816 us; speedup vs baseline: 1.1386x; 1.1386x over previous
//
#include <hip/hip_runtime.h>
#include <math.h>

#define NGRID 70144
#define NV 128
#define JT 16
#define VS 64

__device__ __forceinline__ float4 f4add(float4 a, float4 b){ return make_float4(a.x+b.x, a.y+b.y, a.z+b.z, a.w+b.w); }
__device__ __forceinline__ float4 f4sub(float4 a, float4 b){ return make_float4(a.x-b.x, a.y-b.y, a.z-b.z, a.w-b.w); }

// Offset (in float2 entries) of ring i's twiddle table: sum_{k<i} m_hi(k) * (nlon(k)/2 + 1)
__device__ __forceinline__ long twoff_of(int i){
  long off = 0;
  for(int k=0;k<i;k++){
    int mh = (5+k < 128) ? (5+k) : 128;
    off += (long)mh * (long)(11 + 2*k);
  }
  return off;
}

// tw[m][j] = (cos(2*pi*m*j/N)/N, -sin(2*pi*m*j/N)/N), j = 0..N/2 (folded)
__global__ void fill_tw(float* __restrict__ tw){
  int ring = blockIdx.x, mc = blockIdx.y;
  int N = 20 + 4*ring, H = N/2;
  int mhi = (5+ring < 128) ? (5+ring) : 128;
  int m0 = mc*32;
  if(m0 >= mhi) return;
  int m1 = (m0+32 < mhi) ? (m0+32) : mhi;
  long base = twoff_of(ring);
  int tot = (m1-m0)*(H+1);
  float invN = 1.0f / (float)N;
  for(int idx = threadIdx.x; idx < tot; idx += blockDim.x){
    int m = m0 + idx/(H+1);
    int j = idx % (H+1);
    int p = (m*j) % N;                    // exact integer phase
    float th = 6.2831853071795864f * (float)p * invN;
    float sn, cs;
    __sincosf(th, &sn, &cs);
    long o = (base + (long)(m)*(H+1) + j)*2;
    tw[o]   = cs * invN;
    tw[o+1] = -sn * invN;
  }
}

// Folded DFT: per (ring, m-tile of 32, b, v-half) block.
// Produces G[s][m][n=ring][b][v][ri] for m in tile (m < m_hi(ring)).
// ring = 127 - blockIdx.x so the heavy rings (large JC) are dispatched first.
__global__ __launch_bounds__(256) void dft_fold(const float* __restrict__ x,
                                                const float* __restrict__ tw,
                                                float* __restrict__ G){
  int ring = 127 - blockIdx.x;
  int mt = blockIdx.y;
  int b  = blockIdx.z >> 1;
  int vh = blockIdx.z & 1;
  int N = 20 + 4*ring, H = N/2, JC = H+1;
  int mhi = (5+ring < 128) ? (5+ring) : 128;
  int mbase = mt*32;
  if(mbase >= mhi) return;

  __shared__ __align__(16) float cS[JT][VS], sS[JT][VS], cA[JT][VS], sA[JT][VS];
  __shared__ __align__(16) float twl[JT][32][2];

  int tid = threadIdx.x;
  int vl = tid & 63;          // v within the 64-wide half
  int mg = tid >> 6;          // m-group 0..3 (8 m's each)
  int v  = vh*64 + vl;

  long twbase = twoff_of(ring);
  long offN = (long)ring*(2*ring+18);          // CUMS[ring]
  long a = ring+1;
  long offS = (long)NGRID - a*(2*a+18);        // CUMS[255-ring]
  const float* xn = x + ((long)b*NGRID + offN)*NV + vh*64;
  const float* xs = x + ((long)b*NGRID + offS)*NV + vh*64;

  float aSR[8], aSI[8], aAR[8], aAI[8];
  #pragma unroll
  for(int k=0;k<8;k++){ aSR[k]=0.f; aSI[k]=0.f; aAR[k]=0.f; aAI[k]=0.f; }

  int sjj = tid >> 4;            // staging: jj 0..15
  int sv4 = (tid & 15) << 2;     // staging: v4 0..60
  int tmp2 = (tid & 15) << 1;    // tw staging: m-pair base

  for(int j0=0; j0<JC; j0+=JT){
    __syncthreads();
    // stage folded x tile (exactly one float4 slot per thread)
    {
      int j = j0 + sjj;
      float4 z = make_float4(0.f,0.f,0.f,0.f);
      float4 nj=z, sj=z, np=z, sp=z;
      if(j < JC){
        nj = *(const float4*)&xn[(long)j*NV + sv4];
        sj = *(const float4*)&xs[(long)j*NV + sv4];
        if(j > 0 && j < H){
          int jp = N - j;
          np = *(const float4*)&xn[(long)jp*NV + sv4];
          sp = *(const float4*)&xs[(long)jp*NV + sv4];
        }
      }
      float4 e  = f4add(nj, sj);   // hemi-sum  at j
      float4 o  = f4sub(nj, sj);   // hemi-diff at j
      float4 ep = f4add(np, sp);   // hemi-sum  at N-j (0 at edges)
      float4 op = f4sub(np, sp);
      *(float4*)&cS[sjj][sv4] = f4add(e, ep);
      *(float4*)&sS[sjj][sv4] = f4sub(e, ep);
      *(float4*)&cA[sjj][sv4] = f4add(o, op);
      *(float4*)&sA[sjj][sv4] = f4sub(o, op);
    }
    // stage twiddles: twl[jj][m_loc] as float2 (clamped so reads stay in-table)
    {
      int jsrc = j0 + sjj; if(jsrc > H) jsrc = H;
      int m0s = mbase + tmp2;     if(m0s > mhi-1) m0s = mhi-1;
      int m1s = mbase + tmp2 + 1; if(m1s > mhi-1) m1s = mhi-1;
      float2 t0 = *(const float2*)&tw[(twbase + (long)m0s*JC + jsrc)*2];
      float2 t1 = *(const float2*)&tw[(twbase + (long)m1s*JC + jsrc)*2];
      *(float4*)&twl[sjj][tmp2][0] = make_float4(t0.x, t0.y, t1.x, t1.y);
    }
    __syncthreads();
    int jlim = JC - j0; if(jlim > JT) jlim = JT;
    for(int jj=0; jj<jlim; jj++){
      float c_s = cS[jj][vl], s_s = sS[jj][vl], c_a = cA[jj][vl], s_a = sA[jj][vl];
      const float* twrow = &twl[jj][mg*8][0];
      #pragma unroll
      for(int k2=0; k2<4; k2++){
        float4 t4 = *(const float4*)&twrow[k2*4];   // (cos,-sin) for m_loc, m_loc+1
        aSR[2*k2]   += c_s*t4.x;  aSI[2*k2]   += s_s*t4.y;
        aAR[2*k2]   += c_a*t4.x;  aAI[2*k2]   += s_a*t4.y;
        aSR[2*k2+1] += c_s*t4.z;  aSI[2*k2+1] += s_s*t4.w;
        aAR[2*k2+1] += c_a*t4.z;  aAI[2*k2+1] += s_a*t4.w;
      }
    }
  }
  // write G: [s][m][n][b][v][ri]
  long gb = (long)ring*1024 + (long)b*256 + (long)v*2;
  #pragma unroll
  for(int k=0;k<8;k++){
    int m = mbase + mg*8 + k;
    if(m < mhi){
      long o = (long)m*131072 + gb;
      *(float2*)&G[o]             = make_float2(aSR[k], aSI[k]);
      *(float2*)&G[o + 16777216L] = make_float2(aAR[k], aAI[k]);
    }
  }
}

// Per-(m, b, s) Legendre matmul: out[l][v][ri] = sum_{n>=n0} W[m][l][n] * G[n][v][ri]
__global__ __launch_bounds__(256) void legendre_mm(const float* __restrict__ Wsym,
                                                   const float* __restrict__ Want,
                                                   const float* __restrict__ G,
                                                   float* __restrict__ out){
  int m = blockIdx.x, b = blockIdx.y, s = blockIdx.z;
  const float* W = s ? Want : Wsym;             // [128][64][128]
  __shared__ __align__(16) float Wt[128][68];   // transposed [n][l], padded (row = 272B, 16B-aligned)
  int tid = threadIdx.x;
  const float* Wm = W + (long)m*8192;
  for(int idx=tid; idx<8192; idx+=256){
    int l = idx >> 7, n = idx & 127;
    Wt[n][l] = Wm[idx];
  }
  __syncthreads();
  int v = tid & 127, lh = tid >> 7;
  int n0 = (m-4 > 0) ? (m-4) : 0;               // W[m][l][n]==0 for n<m-4 (mask)
  const float* Gs = G + (long)s*16777216 + (long)m*131072 + (long)b*256 + (long)v*2;
  float aR[32], aI[32];
  #pragma unroll
  for(int q=0;q<32;q++){ aR[q]=0.f; aI[q]=0.f; }
  #pragma unroll 2
  for(int n=n0; n<128; n++){
    float2 g = *(const float2*)&Gs[(long)n*1024];
    const float* wrow = &Wt[n][lh*32];
    #pragma unroll
    for(int q2=0; q2<8; q2++){
      float4 w = *(const float4*)&wrow[q2*4];
      aR[q2*4+0] += w.x*g.x; aI[q2*4+0] += w.x*g.y;
      aR[q2*4+1] += w.y*g.x; aI[q2*4+1] += w.y*g.y;
      aR[q2*4+2] += w.z*g.x; aI[q2*4+2] += w.z*g.y;
      aR[q2*4+3] += w.w*g.x; aI[q2*4+3] += w.w*g.y;
    }
  }
  #pragma unroll
  for(int q=0;q<32;q++){
    int l = lh*32 + q;
    int lf = 2*l + s;                           // interleave sym/anti rows
    long o = (((long)b*128 + lf)*128 + m)*256 + (long)v*2;
    *(float2*)&out[o] = make_float2(aR[q], aI[q]);
  }
}

extern "C" void kernel_launch(void* const* d_in, const int* in_sizes, int n_in,
                              void* d_out, int out_size, void* d_ws, size_t ws_size,
                              hipStream_t stream) {
  const float* x    = (const float*)d_in[0];
  const float* Wsym = (const float*)d_in[1];
  const float* Want = (const float*)d_in[2];
  float* out = (float*)d_out;
  float* ws  = (float*)d_ws;

  // twiddle table size (float2 entries) and aligned G base (floats)
  long two = 0;
  for(int k=0;k<128;k++){ int mh = (5+k<128)?(5+k):128; two += (long)mh*(long)(11+2*k); }
  long GBASE = (two*2 + 255) & ~255L;           // ~12.5 MB tw + 134 MB G in ws

  float* tw = ws;
  float* G  = ws + GBASE;

  hipLaunchKernelGGL(fill_tw,     dim3(128,4),   dim3(256), 0, stream, tw);
  hipLaunchKernelGGL(dft_fold,    dim3(128,4,8), dim3(256), 0, stream, x, tw, G);
  hipLaunchKernelGGL(legendre_mm, dim3(128,4,2), dim3(256), 0, stream, Wsym, Want, G, out);
}

// Round 3
// 417.059 us; speedup vs baseline: 1.1707x; 1.0282x over previous
//
#include <hip/hip_runtime.h>
#include <math.h>

#define NGRID 70144
#define NV 128
#define JT 16
#define VS 64

typedef float f32x4 __attribute__((ext_vector_type(4)));
typedef short short8 __attribute__((ext_vector_type(8)));

__device__ __forceinline__ float4 f4add(float4 a, float4 b){ return make_float4(a.x+b.x, a.y+b.y, a.z+b.z, a.w+b.w); }
__device__ __forceinline__ float4 f4sub(float4 a, float4 b){ return make_float4(a.x-b.x, a.y-b.y, a.z-b.z, a.w-b.w); }

__device__ __forceinline__ unsigned f2bf(float f){
  unsigned u = __float_as_uint(f);
  return (u + 0x7FFFu + ((u>>16)&1u)) >> 16;      // RNE to bf16, returned in low 16
}
__device__ __forceinline__ float bf2f(unsigned h){ return __uint_as_float(h<<16); }

// Offset (in float2 entries) of ring i's twiddle table
__device__ __forceinline__ long twoff_of(int i){
  long off = 0;
  for(int k=0;k<i;k++){
    int mh = (5+k < 128) ? (5+k) : 128;
    off += (long)mh * (long)(11 + 2*k);
  }
  return off;
}

// tw[m][j] = (cos(2*pi*m*j/N)/N, -sin(2*pi*m*j/N)/N), j = 0..N/2 (folded)
__global__ void fill_tw(float* __restrict__ tw){
  int ring = blockIdx.x, mc = blockIdx.y;
  int N = 20 + 4*ring, H = N/2;
  int mhi = (5+ring < 128) ? (5+ring) : 128;
  int m0 = mc*32;
  if(m0 >= mhi) return;
  int m1 = (m0+32 < mhi) ? (m0+32) : mhi;
  long base = twoff_of(ring);
  int tot = (m1-m0)*(H+1);
  float invN = 1.0f / (float)N;
  for(int idx = threadIdx.x; idx < tot; idx += blockDim.x){
    int m = m0 + idx/(H+1);
    int j = idx % (H+1);
    int p = (m*j) % N;                    // exact integer phase
    float th = 6.2831853071795864f * (float)p * invN;
    float sn, cs;
    __sincosf(th, &sn, &cs);
    long o = (base + (long)(m)*(H+1) + j)*2;
    tw[o]   = cs * invN;
    tw[o+1] = -sn * invN;
  }
}

// Folded DFT: per (ring, m-tile of 32, b, v-half) block.
// Produces Gh/Gl (bf16 hi/lo split) [s][m][n=ring][b][v][ri] for m < m_hi(ring).
__global__ __launch_bounds__(256) void dft_fold(const float* __restrict__ x,
                                                const float* __restrict__ tw,
                                                unsigned short* __restrict__ Gh,
                                                unsigned short* __restrict__ Gl){
  int ring = 127 - blockIdx.x;           // heavy rings dispatched first
  int mt = blockIdx.y;
  int b  = blockIdx.z >> 1;
  int vh = blockIdx.z & 1;
  int N = 20 + 4*ring, H = N/2, JC = H+1;
  int mhi = (5+ring < 128) ? (5+ring) : 128;
  int mbase = mt*32;
  if(mbase >= mhi) return;

  __shared__ __align__(16) float cS[JT][VS], sS[JT][VS], cA[JT][VS], sA[JT][VS];
  __shared__ __align__(16) float twl[JT][32][2];

  int tid = threadIdx.x;
  int vl = tid & 63;          // v within the 64-wide half
  int mg = tid >> 6;          // m-group 0..3 (8 m's each)
  int v  = vh*64 + vl;

  long twbase = twoff_of(ring);
  long offN = (long)ring*(2*ring+18);          // CUMS[ring]
  long a = ring+1;
  long offS = (long)NGRID - a*(2*a+18);        // CUMS[255-ring]
  const float* xn = x + ((long)b*NGRID + offN)*NV + vh*64;
  const float* xs = x + ((long)b*NGRID + offS)*NV + vh*64;

  float aSR[8], aSI[8], aAR[8], aAI[8];
  #pragma unroll
  for(int k=0;k<8;k++){ aSR[k]=0.f; aSI[k]=0.f; aAR[k]=0.f; aAI[k]=0.f; }

  int sjj = tid >> 4;            // staging: jj 0..15
  int sv4 = (tid & 15) << 2;     // staging: v4 0..60
  int tmp2 = (tid & 15) << 1;    // tw staging: m-pair base

  for(int j0=0; j0<JC; j0+=JT){
    __syncthreads();
    // stage folded x tile (exactly one float4 slot per thread)
    {
      int j = j0 + sjj;
      float4 z = make_float4(0.f,0.f,0.f,0.f);
      float4 nj=z, sj=z, np=z, sp=z;
      if(j < JC){
        nj = *(const float4*)&xn[(long)j*NV + sv4];
        sj = *(const float4*)&xs[(long)j*NV + sv4];
        if(j > 0 && j < H){
          int jp = N - j;
          np = *(const float4*)&xn[(long)jp*NV + sv4];
          sp = *(const float4*)&xs[(long)jp*NV + sv4];
        }
      }
      float4 e  = f4add(nj, sj);   // hemi-sum  at j
      float4 o  = f4sub(nj, sj);   // hemi-diff at j
      float4 ep = f4add(np, sp);   // hemi-sum  at N-j (0 at edges)
      float4 op = f4sub(np, sp);
      *(float4*)&cS[sjj][sv4] = f4add(e, ep);
      *(float4*)&sS[sjj][sv4] = f4sub(e, ep);
      *(float4*)&cA[sjj][sv4] = f4add(o, op);
      *(float4*)&sA[sjj][sv4] = f4sub(o, op);
    }
    // stage twiddles: twl[jj][m_loc] as float2 (clamped so reads stay in-table)
    {
      int jsrc = j0 + sjj; if(jsrc > H) jsrc = H;
      int m0s = mbase + tmp2;     if(m0s > mhi-1) m0s = mhi-1;
      int m1s = mbase + tmp2 + 1; if(m1s > mhi-1) m1s = mhi-1;
      float2 t0 = *(const float2*)&tw[(twbase + (long)m0s*JC + jsrc)*2];
      float2 t1 = *(const float2*)&tw[(twbase + (long)m1s*JC + jsrc)*2];
      *(float4*)&twl[sjj][tmp2][0] = make_float4(t0.x, t0.y, t1.x, t1.y);
    }
    __syncthreads();
    int jlim = JC - j0; if(jlim > JT) jlim = JT;
    for(int jj=0; jj<jlim; jj++){
      float c_s = cS[jj][vl], s_s = sS[jj][vl], c_a = cA[jj][vl], s_a = sA[jj][vl];
      const float* twrow = &twl[jj][mg*8][0];
      #pragma unroll
      for(int k2=0; k2<4; k2++){
        float4 t4 = *(const float4*)&twrow[k2*4];   // (cos,-sin) for m_loc, m_loc+1
        aSR[2*k2]   += c_s*t4.x;  aSI[2*k2]   += s_s*t4.y;
        aAR[2*k2]   += c_a*t4.x;  aAI[2*k2]   += s_a*t4.y;
        aSR[2*k2+1] += c_s*t4.z;  aSI[2*k2+1] += s_s*t4.w;
        aAR[2*k2+1] += c_a*t4.z;  aAI[2*k2+1] += s_a*t4.w;
      }
    }
  }
  // write Gh/Gl (bf16 split): [s][m][n][b][v][ri], ushort units
  long gb = (long)ring*1024 + (long)b*256 + (long)v*2;
  #pragma unroll
  for(int k=0;k<8;k++){
    int m = mbase + mg*8 + k;
    if(m < mhi){
      long o = (long)m*131072 + gb;
      // sym (s=0)
      unsigned h0 = f2bf(aSR[k]), h1 = f2bf(aSI[k]);
      unsigned l0 = f2bf(aSR[k] - bf2f(h0)), l1 = f2bf(aSI[k] - bf2f(h1));
      *(unsigned*)&Gh[o] = h0 | (h1<<16);
      *(unsigned*)&Gl[o] = l0 | (l1<<16);
      // anti (s=1)
      unsigned a0 = f2bf(aAR[k]), a1 = f2bf(aAI[k]);
      unsigned b0 = f2bf(aAR[k] - bf2f(a0)), b1 = f2bf(aAI[k] - bf2f(a1));
      *(unsigned*)&Gh[o + 16777216L] = a0 | (a1<<16);
      *(unsigned*)&Gl[o + 16777216L] = b0 | (b1<<16);
    }
  }
}

// Split W (fp32) into bf16 hi/lo tables. Layout [s][m][l][n] flat.
__global__ void w_split(const float* __restrict__ Wsym, const float* __restrict__ Want,
                        unsigned short* __restrict__ Wh, unsigned short* __restrict__ Wl){
  long i = (long)blockIdx.x*256 + threadIdx.x;   // 0 .. 2*1048576-1
  const float* W = (i < 1048576) ? Wsym : Want;
  float w = W[i & 1048575];
  unsigned h = f2bf(w);
  unsigned l = f2bf(w - bf2f(h));
  Wh[i] = (unsigned short)h;
  Wl[i] = (unsigned short)l;
}

// Per-(m,b,s) Legendre matmul via split-bf16 MFMA.
// out[l][c] = sum_k W[m][l][k] * G[k][c], c = v*2+ri (256 cols), k = n (128).
__global__ __launch_bounds__(256) void legendre_mfma(const unsigned short* __restrict__ Wh,
                                                     const unsigned short* __restrict__ Wl,
                                                     const unsigned short* __restrict__ Gh,
                                                     const unsigned short* __restrict__ Gl,
                                                     float* __restrict__ out){
  int m = blockIdx.x, b = blockIdx.y, s = blockIdx.z;
  __shared__ __align__(16) unsigned short Bhs[8192];  // [c=256][k=32], octet-XOR-swizzled
  __shared__ __align__(16) unsigned short Bls[8192];
  int tid = threadIdx.x;
  int wave = tid >> 6, lane = tid & 63;
  int j = lane & 15, kb = lane >> 4;

  int kt0 = (m > 4) ? ((m-4) >> 5) : 0;   // W[m][l][n]==0 for n<m-4 -> skip dead k-tiles

  const unsigned short* WA = Wh + (long)(s*128+m)*8192;   // [l][n] 64x128
  const unsigned short* WB = Wl + (long)(s*128+m)*8192;
  long gBase = (long)(s*128+m)*131072 + (long)b*256 + tid;  // staging: this thread owns c=tid

  f32x4 acc[4][4];
  #pragma unroll
  for(int a=0;a<4;a++)
    #pragma unroll
    for(int q=0;q<4;q++) acc[a][q] = (f32x4){0.f,0.f,0.f,0.f};

  for(int kt=kt0; kt<4; ++kt){
    // ---- stage B tile: G[kt*32..+32][c] -> LDS [c][k] with octet swizzle ----
    #pragma unroll
    for(int o=0;o<4;o++){
      long nb = gBase + (long)(kt*32 + o*8)*1024;
      unsigned p0=Gh[nb], p1=Gh[nb+1024], p2=Gh[nb+2048], p3=Gh[nb+3072],
               p4=Gh[nb+4096], p5=Gh[nb+5120], p6=Gh[nb+6144], p7=Gh[nb+7168];
      int4 pk = make_int4((int)(p0|(p1<<16)), (int)(p2|(p3<<16)),
                          (int)(p4|(p5<<16)), (int)(p6|(p7<<16)));
      *(int4*)&Bhs[tid*32 + ((o ^ (tid&3))<<3)] = pk;
      unsigned q0=Gl[nb], q1=Gl[nb+1024], q2=Gl[nb+2048], q3=Gl[nb+3072],
               q4=Gl[nb+4096], q5=Gl[nb+5120], q6=Gl[nb+6144], q7=Gl[nb+7168];
      int4 qk = make_int4((int)(q0|(q1<<16)), (int)(q2|(q3<<16)),
                          (int)(q4|(q5<<16)), (int)(q6|(q7<<16)));
      *(int4*)&Bls[tid*32 + ((o ^ (tid&3))<<3)] = qk;
    }
    __syncthreads();
    // ---- A fragments (direct from global, L1-hot): 4 M-tiles x hi/lo ----
    short8 ah[4], al[4];
    #pragma unroll
    for(int Mt=0;Mt<4;Mt++){
      const unsigned short* ap = WA + (Mt*16 + j)*128 + kt*32 + kb*8;
      ah[Mt] = *(const short8*)ap;
      al[Mt] = *(const short8*)(WB + (Mt*16 + j)*128 + kt*32 + kb*8);
    }
    // ---- MFMA: wave covers N-tiles wave*4..wave*4+3, all 4 M-tiles ----
    #pragma unroll
    for(int nt=0;nt<4;nt++){
      int c = (wave*4+nt)*16 + j;
      short8 bh = *(short8*)&Bhs[c*32 + ((kb ^ (c&3))<<3)];
      short8 bl = *(short8*)&Bls[c*32 + ((kb ^ (c&3))<<3)];
      #pragma unroll
      for(int Mt=0;Mt<4;Mt++){
        acc[Mt][nt] = __builtin_amdgcn_mfma_f32_16x16x32_bf16(ah[Mt], bh, acc[Mt][nt], 0, 0, 0);
        acc[Mt][nt] = __builtin_amdgcn_mfma_f32_16x16x32_bf16(al[Mt], bh, acc[Mt][nt], 0, 0, 0);
        acc[Mt][nt] = __builtin_amdgcn_mfma_f32_16x16x32_bf16(ah[Mt], bl, acc[Mt][nt], 0, 0, 0);
      }
    }
    __syncthreads();
  }
  // ---- epilogue: D lane map col=lane&15, row=(lane>>4)*4+reg ----
  int r4 = (lane>>4)<<2;
  #pragma unroll
  for(int Mt=0;Mt<4;Mt++){
    #pragma unroll
    for(int nt=0;nt<4;nt++){
      int c = (wave*4+nt)*16 + j;
      #pragma unroll
      for(int reg=0;reg<4;reg++){
        int l = Mt*16 + r4 + reg;
        out[((long)(b*128 + 2*l + s)*128 + m)*256 + c] = acc[Mt][nt][reg];
      }
    }
  }
}

extern "C" void kernel_launch(void* const* d_in, const int* in_sizes, int n_in,
                              void* d_out, int out_size, void* d_ws, size_t ws_size,
                              hipStream_t stream) {
  const float* x    = (const float*)d_in[0];
  const float* Wsym = (const float*)d_in[1];
  const float* Want = (const float*)d_in[2];
  float* out = (float*)d_out;
  float* ws  = (float*)d_ws;

  // twiddle table size (float2 entries) and aligned G base (floats)
  long two = 0;
  for(int k=0;k<128;k++){ int mh = (5+k<128)?(5+k):128; two += (long)mh*(long)(11+2*k); }
  long GBASE = (two*2 + 255) & ~255L;           // ~12.2 MB tw region

  float* tw = ws;
  // W bf16 split tables overlap the tw region (tw is dead after dft_fold)
  unsigned short* Wh = (unsigned short*)ws;
  unsigned short* Wl = Wh + 2097152;
  // G bf16 split tables after the tw region: 2 x 33,554,432 ushorts = 134 MB
  unsigned short* Gh = (unsigned short*)(ws + GBASE);
  unsigned short* Gl = Gh + 33554432L;

  hipLaunchKernelGGL(fill_tw,       dim3(128,4),   dim3(256), 0, stream, tw);
  hipLaunchKernelGGL(dft_fold,      dim3(128,4,8), dim3(256), 0, stream, x, tw, Gh, Gl);
  hipLaunchKernelGGL(w_split,       dim3(8192),    dim3(256), 0, stream, Wsym, Want, Wh, Wl);
  hipLaunchKernelGGL(legendre_mfma, dim3(128,4,2), dim3(256), 0, stream, Wh, Wl, Gh, Gl, out);
}

// Round 4
// 415.308 us; speedup vs baseline: 1.1757x; 1.0042x over previous
//
#include <hip/hip_runtime.h>
#include <hip/hip_bf16.h>

#define NGRID 70144
#define NV 128

typedef float f32x4 __attribute__((ext_vector_type(4)));
typedef short short8 __attribute__((ext_vector_type(8)));

__device__ __forceinline__ float4 f4add(float4 a, float4 b){ return make_float4(a.x+b.x, a.y+b.y, a.z+b.z, a.w+b.w); }
__device__ __forceinline__ float4 f4sub(float4 a, float4 b){ return make_float4(a.x-b.x, a.y-b.y, a.z-b.z, a.w-b.w); }

__device__ __forceinline__ unsigned f2bf(float f){
  return (unsigned)__bfloat16_as_ushort(__float2bfloat16(f));   // RNE
}
__device__ __forceinline__ float bf2f(unsigned h){ return __uint_as_float(h<<16); }
__device__ __forceinline__ unsigned packsplit(float f){
  unsigned h = f2bf(f);
  unsigned l = f2bf(f - bf2f(h));
  return (h<<16) | l;
}
__device__ __forceinline__ int swzc(int c){ return (c ^ (c>>3)) & 7; }

// unpack 8 packed (hi<<16|lo) words (k-order) into bf16 hi/lo fragments
__device__ __forceinline__ void unpack_frag(int4 a, int4 b, short8 &bh, short8 &bl){
  int h0 = (int)(((unsigned)a.x >> 16) | ((unsigned)a.y & 0xFFFF0000u));
  int h1 = (int)(((unsigned)a.z >> 16) | ((unsigned)a.w & 0xFFFF0000u));
  int h2 = (int)(((unsigned)b.x >> 16) | ((unsigned)b.y & 0xFFFF0000u));
  int h3 = (int)(((unsigned)b.z >> 16) | ((unsigned)b.w & 0xFFFF0000u));
  int l0 = (int)(((unsigned)a.x & 0xFFFFu) | ((unsigned)a.y << 16));
  int l1 = (int)(((unsigned)a.z & 0xFFFFu) | ((unsigned)a.w << 16));
  int l2 = (int)(((unsigned)b.x & 0xFFFFu) | ((unsigned)b.y << 16));
  int l3 = (int)(((unsigned)b.z & 0xFFFFu) | ((unsigned)b.w << 16));
  int4 H = make_int4(h0,h1,h2,h3), L = make_int4(l0,l1,l2,l3);
  bh = *(short8*)&H; bl = *(short8*)&L;
}

// Padded per-ring twiddle slabs: [cos_hi|cos_lo|sin_hi|sin_lo][Mpad][Kpad] bf16.
// value(m,j) = cos/-sin(2*pi*(m*j mod N)/N) / N; zero outside (mhi, JC).
__global__ void fill_tw(unsigned short* __restrict__ twA){
  int ring = blockIdx.x, t = blockIdx.y;     // t: 0=cos, 1=sin
  int N = 20+4*ring, H = N/2, JC = H+1;
  int mhi = (5+ring<128)?(5+ring):128;
  int Mpad = ((mhi+15)>>4)<<4;
  int Kpad = ((JC+31)>>5)<<5;
  long off = 0;
  for(int r=0;r<ring;r++){
    int mh=(5+r<128)?(5+r):128, jc=11+2*r;
    off += 4L*(((mh+15)>>4)<<4)*(((jc+31)>>5)<<5);
  }
  long MK = (long)Mpad*Kpad;
  unsigned short* hiT = twA + off + (long)(t*2)*MK;
  unsigned short* loT = hiT + MK;
  float invN = 1.0f/(float)N;
  for(long idx = threadIdx.x; idx < MK; idx += 256){
    int m = (int)(idx / Kpad), j = (int)(idx % Kpad);
    float val = 0.f;
    if(m < mhi && j < JC){
      int p = (m*j) % N;                     // exact integer phase
      float th = 6.2831853071795864f * (float)p * invN;
      float sn, cs; __sincosf(th,&sn,&cs);
      val = (t ? -sn : cs) * invN;
    }
    unsigned h = f2bf(val);
    unsigned l = f2bf(val - bf2f(h));
    hiT[idx] = (unsigned short)h;
    loT[idx] = (unsigned short)l;
  }
}

// Folded ragged DFT as split-bf16 MFMA GEMM.
// Block: (ring, type=re/im, batch). out[m][c] = sum_j twA[m][j]*fold[j][c],
// cols c = v*2 + fold_parity (sym/anti). Writes Gp[s][ri][m][n][b][v] packed u32.
__global__ __launch_bounds__(256) void dft_mfma(const float* __restrict__ x,
                                                const unsigned short* __restrict__ twA,
                                                unsigned* __restrict__ Gp){
  int bx = blockIdx.x;
  int ring = 127 - (bx >> 1);               // heavy rings first
  int type = bx & 1;                        // 0: re (cos), 1: im (-sin)
  int b = blockIdx.y;
  int N = 20+4*ring, H = N/2, JC = H+1;
  int mhi = (5+ring<128)?(5+ring):128;
  int Mt_n = (mhi+15)>>4;
  int KT = (JC+31)>>5;
  int Kpad = KT<<5;
  int Mpad = Mt_n<<4;

  long off = 0;
  for(int r=0;r<ring;r++){
    int mh=(5+r<128)?(5+r):128, jc=11+2*r;
    off += 4L*(((mh+15)>>4)<<4)*(((jc+31)>>5)<<5);
  }
  long MK = (long)Mpad*Kpad;
  const unsigned short* Ahi = twA + off + (long)(type*2)*MK;
  const unsigned short* Alo = Ahi + MK;

  const float* xn = x + ((long)b*NGRID + (long)ring*(2*ring+18))*NV;
  long a1 = ring+1;
  const float* xs = x + ((long)b*NGRID + (NGRID - a1*(2*a1+18)))*NV;

  __shared__ __align__(16) unsigned Bp[8192];   // [c=256][k=32] u32-packed, XOR-swizzled

  int tid = threadIdx.x;
  int jb = tid >> 5, vp = tid & 31;             // staging: 8 j-blocks x 32 v-quads
  int wave = tid >> 6, lane = tid & 63;
  int jj = lane & 15, kb = lane >> 4;

  f32x4 acc[8][4];
  #pragma unroll
  for(int Mt=0;Mt<8;Mt++)
    #pragma unroll
    for(int ct=0;ct<4;ct++) acc[Mt][ct] = (f32x4){0.f,0.f,0.f,0.f};

  for(int kt=0; kt<KT; ++kt){
    __syncthreads();
    // ---- stage fold tile: 4 j-rows x 4 v per thread -> 8 b128 LDS writes ----
    float4 fS[4], fA[4];
    #pragma unroll
    for(int dj=0;dj<4;dj++){
      int j = kt*32 + jb*4 + dj;
      float4 z = make_float4(0.f,0.f,0.f,0.f);
      float4 nj=z, sj=z, np=z, sp=z;
      if(j < JC){
        nj = *(const float4*)&xn[(long)j*NV + vp*4];
        sj = *(const float4*)&xs[(long)j*NV + vp*4];
        if(j > 0 && j < H){
          int jp = N - j;
          np = *(const float4*)&xn[(long)jp*NV + vp*4];
          sp = *(const float4*)&xs[(long)jp*NV + vp*4];
        }
      }
      float4 e  = f4add(nj, sj), o  = f4sub(nj, sj);
      float4 ep = f4add(np, sp), op = f4sub(np, sp);
      fS[dj] = type ? f4sub(e, ep) : f4add(e, ep);   // sym fold (c-parity 0)
      fA[dj] = type ? f4sub(o, op) : f4add(o, op);   // anti fold (c-parity 1)
    }
    #pragma unroll
    for(int dv=0;dv<4;dv++){
      int c0 = (vp*4+dv)*2;
      int4 wS = make_int4((int)packsplit(((const float*)&fS[0])[dv]),
                          (int)packsplit(((const float*)&fS[1])[dv]),
                          (int)packsplit(((const float*)&fS[2])[dv]),
                          (int)packsplit(((const float*)&fS[3])[dv]));
      *(int4*)&Bp[c0*32 + ((jb*4) ^ (swzc(c0)<<2))] = wS;
      int c1 = c0 + 1;
      int4 wA = make_int4((int)packsplit(((const float*)&fA[0])[dv]),
                          (int)packsplit(((const float*)&fA[1])[dv]),
                          (int)packsplit(((const float*)&fA[2])[dv]),
                          (int)packsplit(((const float*)&fA[3])[dv]));
      *(int4*)&Bp[c1*32 + ((jb*4) ^ (swzc(c1)<<2))] = wA;
    }
    __syncthreads();
    // ---- B fragments for this wave's 4 col-tiles ----
    short8 bh[4], bl[4];
    #pragma unroll
    for(int ct=0;ct<4;ct++){
      int c = wave*64 + ct*16 + jj;
      int sw = swzc(c)<<2;
      int4 pa = *(const int4*)&Bp[c*32 + ((kb*8) ^ sw)];
      int4 pb = *(const int4*)&Bp[c*32 + ((kb*8+4) ^ sw)];
      unpack_frag(pa, pb, bh[ct], bl[ct]);
    }
    // ---- A fragments (global, L2-hot) + MFMA ----
    #pragma unroll
    for(int Mt=0;Mt<8;Mt++){
      if(Mt < Mt_n){
        long ao = (long)(Mt*16 + jj)*Kpad + kt*32 + kb*8;
        short8 ah = *(const short8*)&Ahi[ao];
        short8 al = *(const short8*)&Alo[ao];
        #pragma unroll
        for(int ct=0;ct<4;ct++){
          acc[Mt][ct] = __builtin_amdgcn_mfma_f32_16x16x32_bf16(ah, bh[ct], acc[Mt][ct], 0,0,0);
          acc[Mt][ct] = __builtin_amdgcn_mfma_f32_16x16x32_bf16(al, bh[ct], acc[Mt][ct], 0,0,0);
          acc[Mt][ct] = __builtin_amdgcn_mfma_f32_16x16x32_bf16(ah, bl[ct], acc[Mt][ct], 0,0,0);
        }
      }
    }
  }
  // ---- epilogue: D col=lane&15, row=kb*4+reg; Gp[s][ri][m][n][b][v] u32 ----
  #pragma unroll
  for(int Mt=0;Mt<8;Mt++){
    if(Mt < Mt_n){
      #pragma unroll
      for(int ct=0;ct<4;ct++){
        int c = wave*64 + ct*16 + jj;
        int s = c & 1, v = c >> 1;
        #pragma unroll
        for(int reg=0;reg<4;reg++){
          int m = Mt*16 + (kb<<2) + reg;
          if(m < mhi){
            Gp[(long)((s*2+type)*128 + m)*65536 + (long)ring*512 + b*128 + v]
              = packsplit(acc[Mt][ct][reg]);
          }
        }
      }
    }
  }
}

// Split W (fp32) into bf16 hi/lo tables. Layout [s][m][l][n] flat.
__global__ void w_split(const float* __restrict__ Wsym, const float* __restrict__ Want,
                        unsigned short* __restrict__ Wh, unsigned short* __restrict__ Wl){
  long i = (long)blockIdx.x*256 + threadIdx.x;   // 0 .. 2*1048576-1
  const float* W = (i < 1048576) ? Wsym : Want;
  float w = W[i & 1048575];
  unsigned h = f2bf(w);
  unsigned l = f2bf(w - bf2f(h));
  Wh[i] = (unsigned short)h;
  Wl[i] = (unsigned short)l;
}

// Per-(m,b,s) Legendre matmul via split-bf16 MFMA.
// out[l][c] = sum_n W[m][l][n] * G[n][c], c = v*2+ri (256 cols).
__global__ __launch_bounds__(256) void legendre_mfma(const unsigned short* __restrict__ Wh,
                                                     const unsigned short* __restrict__ Wl,
                                                     const unsigned* __restrict__ Gp,
                                                     float* __restrict__ out){
  int m = blockIdx.x, b = blockIdx.y, s = blockIdx.z;
  __shared__ __align__(16) unsigned Bp[8192];   // [c=256][k=32] u32-packed, XOR-swizzled
  int tid = threadIdx.x;
  int wave = tid >> 6, lane = tid & 63;
  int jj = lane & 15, kb = lane >> 4;

  int kt0 = (m > 4) ? ((m-4) >> 5) : 0;         // W[m][l][n]==0 for n<m-4

  const unsigned short* WA = Wh + (long)(s*128+m)*8192;   // [l][n] 64x128
  const unsigned short* WB = Wl + (long)(s*128+m)*8192;
  int ri = tid & 1, v = tid >> 1;
  long gC0 = (long)((s*2+ri)*128 + m)*65536 + (long)b*128 + v;  // + n*512

  f32x4 acc[4][4];
  #pragma unroll
  for(int a=0;a<4;a++)
    #pragma unroll
    for(int q=0;q<4;q++) acc[a][q] = (f32x4){0.f,0.f,0.f,0.f};

  int swT = swzc(tid)<<2;
  for(int kt=kt0; kt<4; ++kt){
    __syncthreads();
    // ---- stage B tile: 32 coalesced u32 loads -> 8 b128 LDS writes ----
    #pragma unroll
    for(int k4=0;k4<32;k4+=4){
      int4 w = make_int4((int)Gp[gC0 + (long)(kt*32+k4+0)*512],
                         (int)Gp[gC0 + (long)(kt*32+k4+1)*512],
                         (int)Gp[gC0 + (long)(kt*32+k4+2)*512],
                         (int)Gp[gC0 + (long)(kt*32+k4+3)*512]);
      *(int4*)&Bp[tid*32 + (k4 ^ swT)] = w;
    }
    __syncthreads();
    // ---- B fragments ----
    short8 bh[4], bl[4];
    #pragma unroll
    for(int nt=0;nt<4;nt++){
      int c = (wave*4+nt)*16 + jj;
      int sw = swzc(c)<<2;
      int4 pa = *(const int4*)&Bp[c*32 + ((kb*8) ^ sw)];
      int4 pb = *(const int4*)&Bp[c*32 + ((kb*8+4) ^ sw)];
      unpack_frag(pa, pb, bh[nt], bl[nt]);
    }
    // ---- A fragments (direct global, L1/L2-hot) + MFMA ----
    #pragma unroll
    for(int Mt=0;Mt<4;Mt++){
      long ao = (long)(Mt*16 + jj)*128 + kt*32 + kb*8;
      short8 ah = *(const short8*)&WA[ao];
      short8 al = *(const short8*)&WB[ao];
      #pragma unroll
      for(int nt=0;nt<4;nt++){
        acc[Mt][nt] = __builtin_amdgcn_mfma_f32_16x16x32_bf16(ah, bh[nt], acc[Mt][nt], 0,0,0);
        acc[Mt][nt] = __builtin_amdgcn_mfma_f32_16x16x32_bf16(al, bh[nt], acc[Mt][nt], 0,0,0);
        acc[Mt][nt] = __builtin_amdgcn_mfma_f32_16x16x32_bf16(ah, bl[nt], acc[Mt][nt], 0,0,0);
      }
    }
  }
  // ---- epilogue ----
  int r4 = (lane>>4)<<2;
  #pragma unroll
  for(int Mt=0;Mt<4;Mt++){
    #pragma unroll
    for(int nt=0;nt<4;nt++){
      int c = (wave*4+nt)*16 + jj;
      #pragma unroll
      for(int reg=0;reg<4;reg++){
        int l = Mt*16 + r4 + reg;
        out[((long)(b*128 + 2*l + s)*128 + m)*256 + c] = acc[Mt][nt][reg];
      }
    }
  }
}

extern "C" void kernel_launch(void* const* d_in, const int* in_sizes, int n_in,
                              void* d_out, int out_size, void* d_ws, size_t ws_size,
                              hipStream_t stream) {
  const float* x    = (const float*)d_in[0];
  const float* Wsym = (const float*)d_in[1];
  const float* Want = (const float*)d_in[2];
  float* out = (float*)d_out;

  // twiddle slab total (ushorts)
  long TWA = 0;
  for(int r=0;r<128;r++){
    int mh=(5+r<128)?(5+r):128, jc=11+2*r;
    TWA += 4L*(((mh+15)/16)*16)*(((jc+31)/32)*32);
  }
  size_t gpOffB = (size_t)TWA*2;
  if(gpOffB < 8388608) gpOffB = 8388608;        // keep room for Wh/Wl overlap
  gpOffB = (gpOffB + 255) & ~(size_t)255;

  unsigned short* twA = (unsigned short*)d_ws;
  unsigned* Gp = (unsigned*)((char*)d_ws + gpOffB);     // 134 MB packed G
  unsigned short* Wh = (unsigned short*)d_ws;           // overlaps twA (dead after dft)
  unsigned short* Wl = Wh + 2097152;

  hipLaunchKernelGGL(fill_tw,       dim3(128,2),   dim3(256), 0, stream, twA);
  hipLaunchKernelGGL(dft_mfma,      dim3(256,4),   dim3(256), 0, stream, x, twA, Gp);
  hipLaunchKernelGGL(w_split,       dim3(8192),    dim3(256), 0, stream, Wsym, Want, Wh, Wl);
  hipLaunchKernelGGL(legendre_mfma, dim3(128,4,2), dim3(256), 0, stream, Wh, Wl, Gp, out);
}

// Round 5
// 386.479 us; speedup vs baseline: 1.2634x; 1.0746x over previous
//
#include <hip/hip_runtime.h>
#include <hip/hip_bf16.h>

#define NGRID 70144
#define NV 128

typedef float f32x4 __attribute__((ext_vector_type(4)));
typedef short short8 __attribute__((ext_vector_type(8)));

__device__ __forceinline__ float4 f4add(float4 a, float4 b){ return make_float4(a.x+b.x, a.y+b.y, a.z+b.z, a.w+b.w); }
__device__ __forceinline__ float4 f4sub(float4 a, float4 b){ return make_float4(a.x-b.x, a.y-b.y, a.z-b.z, a.w-b.w); }

__device__ __forceinline__ unsigned f2bf(float f){
  return (unsigned)__bfloat16_as_ushort(__float2bfloat16(f));   // RNE
}
__device__ __forceinline__ float bf2f(unsigned h){ return __uint_as_float(h<<16); }
__device__ __forceinline__ unsigned packsplit(float f){
  unsigned h = f2bf(f);
  unsigned l = f2bf(f - bf2f(h));
  return (h<<16) | l;
}
__device__ __forceinline__ int swzc(int c){ return (c ^ (c>>3)) & 7; }

__device__ __forceinline__ void unpack_frag(int4 a, int4 b, short8 &bh, short8 &bl){
  int h0 = (int)(((unsigned)a.x >> 16) | ((unsigned)a.y & 0xFFFF0000u));
  int h1 = (int)(((unsigned)a.z >> 16) | ((unsigned)a.w & 0xFFFF0000u));
  int h2 = (int)(((unsigned)b.x >> 16) | ((unsigned)b.y & 0xFFFF0000u));
  int h3 = (int)(((unsigned)b.z >> 16) | ((unsigned)b.w & 0xFFFF0000u));
  int l0 = (int)(((unsigned)a.x & 0xFFFFu) | ((unsigned)a.y << 16));
  int l1 = (int)(((unsigned)a.z & 0xFFFFu) | ((unsigned)a.w << 16));
  int l2 = (int)(((unsigned)b.x & 0xFFFFu) | ((unsigned)b.y << 16));
  int l3 = (int)(((unsigned)b.z & 0xFFFFu) | ((unsigned)b.w << 16));
  int4 H = make_int4(h0,h1,h2,h3), L = make_int4(l0,l1,l2,l3);
  bh = *(short8*)&H; bl = *(short8*)&L;
}

// ---------- compile-time tables ----------
struct TileT { unsigned char ring, type, mc; };
constexpr int calc_ntiles(){
  int n=0;
  for(int r=0;r<128;r++){
    int mhi=(5+r<128)?(5+r):128;
    int mtn=(mhi+15)/16;
    n += 2*((mtn+3)/4);
  }
  return n;
}
constexpr int NTILES = calc_ntiles();
struct Tiles { TileT t[NTILES]; };
constexpr Tiles make_tiles(){
  Tiles T{}; int k=0;
  for(int r=127;r>=0;r--){            // heavy rings first
    int mhi=(5+r<128)?(5+r):128;
    int mtn=(mhi+15)/16;
    int nc=(mtn+3)/4;
    for(int mc=0;mc<nc;mc++)
      for(int tp=0;tp<2;tp++){
        T.t[k].ring=(unsigned char)r; T.t[k].type=(unsigned char)tp; T.t[k].mc=(unsigned char)mc; k++;
      }
  }
  return T;
}
__constant__ Tiles TILES = make_tiles();

struct Offs { long o[129]; };
constexpr Offs make_offs(){
  Offs O{}; long off=0;
  for(int r=0;r<128;r++){
    O.o[r]=off;
    int mh=(5+r<128)?(5+r):128, jc=11+2*r;
    off += 4L*(((mh+15)/16)*16)*(((jc+31)/32)*32);
  }
  O.o[128]=off;
  return O;
}
__constant__ Offs TWOFF = make_offs();
constexpr long TWATOT = make_offs().o[128];   // total ushorts in twiddle slabs

// Padded per-ring twiddle slabs: [cos_hi|cos_lo|sin_hi|sin_lo][Mpad][Kpad] bf16.
__global__ void fill_tw(unsigned short* __restrict__ twA){
  int ring = blockIdx.x, t = blockIdx.y;     // t: 0=cos, 1=sin
  int N = 20+4*ring, H = N/2, JC = H+1;
  int mhi = (5+ring<128)?(5+ring):128;
  int Mpad = ((mhi+15)>>4)<<4;
  int Kpad = ((JC+31)>>5)<<5;
  long MK = (long)Mpad*Kpad;
  unsigned short* hiT = twA + TWOFF.o[ring] + (long)(t*2)*MK;
  unsigned short* loT = hiT + MK;
  float invN = 1.0f/(float)N;
  int tid = threadIdx.x;
  for(int m=0;m<Mpad;m++){
    int p0   = (int)(((long)m*tid) % N);
    int step = (int)(((long)m*256) % N);
    int p = p0;
    for(int j=tid;j<Kpad;j+=256){
      float val = 0.f;
      if(m < mhi && j < JC){
        float th = 6.2831853071795864f * (float)p * invN;
        float sn, cs; __sincosf(th,&sn,&cs);
        val = (t ? -sn : cs) * invN;
      }
      unsigned h = f2bf(val);
      unsigned l = f2bf(val - bf2f(h));
      long idx = (long)m*Kpad + j;
      hiT[idx] = (unsigned short)h;
      loT[idx] = (unsigned short)l;
      p += step; if(p>=N) p-=N;
    }
  }
}

// Folded ragged DFT as split-bf16 MFMA GEMM, M-chunked + statically balanced.
// Tile: (ring, type=re/im, m-chunk of <=4 16-row tiles); blockIdx.y = batch.
__global__ __launch_bounds__(256,3) void dft_mfma(const float* __restrict__ x,
                                                  const unsigned short* __restrict__ twA,
                                                  unsigned* __restrict__ Gp){
  TileT tl = TILES.t[blockIdx.x];
  int ring = tl.ring, type = tl.type;
  int b = blockIdx.y;
  int N = 20+4*ring, H = N/2, JC = H+1;
  int mhi = (5+ring<128)?(5+ring):128;
  int MtN = (mhi+15)>>4;
  int Mt0 = tl.mc*4;
  int KT = (JC+31)>>5;
  int Kpad = KT<<5;
  int Mpad = MtN<<4;

  long MK = (long)Mpad*Kpad;
  const unsigned short* Ahi = twA + TWOFF.o[ring] + (long)(type*2)*MK;
  const unsigned short* Alo = Ahi + MK;

  const float* xn = x + ((long)b*NGRID + (long)ring*(2*ring+18))*NV;
  long a1 = ring+1;
  const float* xs = x + ((long)b*NGRID + (NGRID - a1*(2*a1+18)))*NV;

  __shared__ __align__(16) unsigned Bp[8192];   // [c=256][k=32] u32-packed, XOR-swizzled

  int tid = threadIdx.x;
  int jb = tid >> 5, vp = tid & 31;             // staging: 8 j-blocks x 32 v-quads
  int wave = tid >> 6, lane = tid & 63;
  int jj = lane & 15, kb = lane >> 4;

  f32x4 acc[4][4];
  #pragma unroll
  for(int Mt=0;Mt<4;Mt++)
    #pragma unroll
    for(int ct=0;ct<4;ct++) acc[Mt][ct] = (f32x4){0.f,0.f,0.f,0.f};

  for(int kt=0; kt<KT; ++kt){
    __syncthreads();
    // ---- stage fold tile: 4 j-rows x 4 v per thread -> 8 b128 LDS writes ----
    float4 fS[4], fA[4];
    #pragma unroll
    for(int dj=0;dj<4;dj++){
      int j = kt*32 + jb*4 + dj;
      float4 z = make_float4(0.f,0.f,0.f,0.f);
      float4 nj=z, sj=z, np=z, sp=z;
      if(j < JC){
        nj = *(const float4*)&xn[(long)j*NV + vp*4];
        sj = *(const float4*)&xs[(long)j*NV + vp*4];
        if(j > 0 && j < H){
          int jp = N - j;
          np = *(const float4*)&xn[(long)jp*NV + vp*4];
          sp = *(const float4*)&xs[(long)jp*NV + vp*4];
        }
      }
      float4 e  = f4add(nj, sj), o  = f4sub(nj, sj);
      float4 ep = f4add(np, sp), op = f4sub(np, sp);
      fS[dj] = type ? f4sub(e, ep) : f4add(e, ep);   // sym fold (c-parity 0)
      fA[dj] = type ? f4sub(o, op) : f4add(o, op);   // anti fold (c-parity 1)
    }
    #pragma unroll
    for(int dv=0;dv<4;dv++){
      int c0 = (vp*4+dv)*2;
      int4 wS = make_int4((int)packsplit(((const float*)&fS[0])[dv]),
                          (int)packsplit(((const float*)&fS[1])[dv]),
                          (int)packsplit(((const float*)&fS[2])[dv]),
                          (int)packsplit(((const float*)&fS[3])[dv]));
      *(int4*)&Bp[c0*32 + ((jb*4) ^ (swzc(c0)<<2))] = wS;
      int c1 = c0 + 1;
      int4 wA = make_int4((int)packsplit(((const float*)&fA[0])[dv]),
                          (int)packsplit(((const float*)&fA[1])[dv]),
                          (int)packsplit(((const float*)&fA[2])[dv]),
                          (int)packsplit(((const float*)&fA[3])[dv]));
      *(int4*)&Bp[c1*32 + ((jb*4) ^ (swzc(c1)<<2))] = wA;
    }
    __syncthreads();
    // ---- B fragments for this wave's 4 col-tiles ----
    short8 bh[4], bl[4];
    #pragma unroll
    for(int ct=0;ct<4;ct++){
      int c = wave*64 + ct*16 + jj;
      int sw = swzc(c)<<2;
      int4 pa = *(const int4*)&Bp[c*32 + ((kb*8) ^ sw)];
      int4 pb = *(const int4*)&Bp[c*32 + ((kb*8+4) ^ sw)];
      unpack_frag(pa, pb, bh[ct], bl[ct]);
    }
    // ---- A fragments (global, L2-hot) + MFMA over this block's m-chunk ----
    #pragma unroll
    for(int Mt=0;Mt<4;Mt++){
      if(Mt0+Mt < MtN){
        long ao = (long)((Mt0+Mt)*16 + jj)*Kpad + kt*32 + kb*8;
        short8 ah = *(const short8*)&Ahi[ao];
        short8 al = *(const short8*)&Alo[ao];
        #pragma unroll
        for(int ct=0;ct<4;ct++){
          acc[Mt][ct] = __builtin_amdgcn_mfma_f32_16x16x32_bf16(ah, bh[ct], acc[Mt][ct], 0,0,0);
          acc[Mt][ct] = __builtin_amdgcn_mfma_f32_16x16x32_bf16(al, bh[ct], acc[Mt][ct], 0,0,0);
          acc[Mt][ct] = __builtin_amdgcn_mfma_f32_16x16x32_bf16(ah, bl[ct], acc[Mt][ct], 0,0,0);
        }
      }
    }
  }
  // ---- epilogue: D col=lane&15, row=kb*4+reg; Gp[s][ri][m][n][b][v] u32 ----
  #pragma unroll
  for(int Mt=0;Mt<4;Mt++){
    if(Mt0+Mt < MtN){
      #pragma unroll
      for(int ct=0;ct<4;ct++){
        int c = wave*64 + ct*16 + jj;
        int s = c & 1, v = c >> 1;
        #pragma unroll
        for(int reg=0;reg<4;reg++){
          int m = (Mt0+Mt)*16 + (kb<<2) + reg;
          if(m < mhi){
            Gp[(long)((s*2+type)*128 + m)*65536 + (long)ring*512 + b*128 + v]
              = packsplit(acc[Mt][ct][reg]);
          }
        }
      }
    }
  }
}

// Split W (fp32) into bf16 hi/lo tables. Layout [s][m][l][n] flat.
__global__ void w_split(const float* __restrict__ Wsym, const float* __restrict__ Want,
                        unsigned short* __restrict__ Wh, unsigned short* __restrict__ Wl){
  long i = (long)blockIdx.x*256 + threadIdx.x;   // 0 .. 2*1048576-1
  const float* W = (i < 1048576) ? Wsym : Want;
  float w = W[i & 1048575];
  unsigned h = f2bf(w);
  unsigned l = f2bf(w - bf2f(h));
  Wh[i] = (unsigned short)h;
  Wl[i] = (unsigned short)l;
}

// Per-(m,b,s) Legendre matmul via split-bf16 MFMA.
__global__ __launch_bounds__(256) void legendre_mfma(const unsigned short* __restrict__ Wh,
                                                     const unsigned short* __restrict__ Wl,
                                                     const unsigned* __restrict__ Gp,
                                                     float* __restrict__ out){
  int m = blockIdx.x, b = blockIdx.y, s = blockIdx.z;
  __shared__ __align__(16) unsigned Bp[8192];   // [c=256][k=32] u32-packed, XOR-swizzled
  int tid = threadIdx.x;
  int wave = tid >> 6, lane = tid & 63;
  int jj = lane & 15, kb = lane >> 4;

  int kt0 = (m > 4) ? ((m-4) >> 5) : 0;         // W[m][l][n]==0 for n<m-4

  const unsigned short* WA = Wh + (long)(s*128+m)*8192;   // [l][n] 64x128
  const unsigned short* WB = Wl + (long)(s*128+m)*8192;
  int ri = tid & 1, v = tid >> 1;
  long gC0 = (long)((s*2+ri)*128 + m)*65536 + (long)b*128 + v;  // + n*512

  f32x4 acc[4][4];
  #pragma unroll
  for(int a=0;a<4;a++)
    #pragma unroll
    for(int q=0;q<4;q++) acc[a][q] = (f32x4){0.f,0.f,0.f,0.f};

  int swT = swzc(tid)<<2;
  for(int kt=kt0; kt<4; ++kt){
    __syncthreads();
    #pragma unroll
    for(int k4=0;k4<32;k4+=4){
      int4 w = make_int4((int)Gp[gC0 + (long)(kt*32+k4+0)*512],
                         (int)Gp[gC0 + (long)(kt*32+k4+1)*512],
                         (int)Gp[gC0 + (long)(kt*32+k4+2)*512],
                         (int)Gp[gC0 + (long)(kt*32+k4+3)*512]);
      *(int4*)&Bp[tid*32 + (k4 ^ swT)] = w;
    }
    __syncthreads();
    short8 bh[4], bl[4];
    #pragma unroll
    for(int nt=0;nt<4;nt++){
      int c = (wave*4+nt)*16 + jj;
      int sw = swzc(c)<<2;
      int4 pa = *(const int4*)&Bp[c*32 + ((kb*8) ^ sw)];
      int4 pb = *(const int4*)&Bp[c*32 + ((kb*8+4) ^ sw)];
      unpack_frag(pa, pb, bh[nt], bl[nt]);
    }
    #pragma unroll
    for(int Mt=0;Mt<4;Mt++){
      long ao = (long)(Mt*16 + jj)*128 + kt*32 + kb*8;
      short8 ah = *(const short8*)&WA[ao];
      short8 al = *(const short8*)&WB[ao];
      #pragma unroll
      for(int nt=0;nt<4;nt++){
        acc[Mt][nt] = __builtin_amdgcn_mfma_f32_16x16x32_bf16(ah, bh[nt], acc[Mt][nt], 0,0,0);
        acc[Mt][nt] = __builtin_amdgcn_mfma_f32_16x16x32_bf16(al, bh[nt], acc[Mt][nt], 0,0,0);
        acc[Mt][nt] = __builtin_amdgcn_mfma_f32_16x16x32_bf16(ah, bl[nt], acc[Mt][nt], 0,0,0);
      }
    }
  }
  int r4 = (lane>>4)<<2;
  #pragma unroll
  for(int Mt=0;Mt<4;Mt++){
    #pragma unroll
    for(int nt=0;nt<4;nt++){
      int c = (wave*4+nt)*16 + jj;
      #pragma unroll
      for(int reg=0;reg<4;reg++){
        int l = Mt*16 + r4 + reg;
        out[((long)(b*128 + 2*l + s)*128 + m)*256 + c] = acc[Mt][nt][reg];
      }
    }
  }
}

extern "C" void kernel_launch(void* const* d_in, const int* in_sizes, int n_in,
                              void* d_out, int out_size, void* d_ws, size_t ws_size,
                              hipStream_t stream) {
  const float* x    = (const float*)d_in[0];
  const float* Wsym = (const float*)d_in[1];
  const float* Want = (const float*)d_in[2];
  float* out = (float*)d_out;

  size_t gpOffB = (size_t)TWATOT*2;
  if(gpOffB < 8388608) gpOffB = 8388608;        // keep room for Wh/Wl overlap
  gpOffB = (gpOffB + 255) & ~(size_t)255;

  unsigned short* twA = (unsigned short*)d_ws;
  unsigned* Gp = (unsigned*)((char*)d_ws + gpOffB);     // 134 MB packed G
  unsigned short* Wh = (unsigned short*)d_ws;           // overlaps twA (dead after dft)
  unsigned short* Wl = Wh + 2097152;

  hipLaunchKernelGGL(fill_tw,       dim3(128,2),     dim3(256), 0, stream, twA);
  hipLaunchKernelGGL(dft_mfma,      dim3(NTILES,4),  dim3(256), 0, stream, x, twA, Gp);
  hipLaunchKernelGGL(w_split,       dim3(8192),      dim3(256), 0, stream, Wsym, Want, Wh, Wl);
  hipLaunchKernelGGL(legendre_mfma, dim3(128,4,2),   dim3(256), 0, stream, Wh, Wl, Gp, out);
}

// Round 8
// 358.792 us; speedup vs baseline: 1.3609x; 1.0772x over previous
//
#include <hip/hip_runtime.h>
#include <hip/hip_bf16.h>

#define NGRID 70144
#define NV 128

typedef float f32x4 __attribute__((ext_vector_type(4)));
typedef short short8 __attribute__((ext_vector_type(8)));

__device__ __forceinline__ unsigned f2bf(float f){
  return (unsigned)__bfloat16_as_ushort(__float2bfloat16(f));   // RNE
}
__device__ __forceinline__ float bf2f(unsigned h){ return __uint_as_float(h<<16); }
__device__ __forceinline__ unsigned packsplit(float f){
  unsigned h = f2bf(f);
  unsigned l = f2bf(f - bf2f(h));
  return (h<<16) | l;
}
__device__ __forceinline__ int swzc(int c){ return (c ^ (c>>3)) & 7; }

__device__ __forceinline__ void unpack_frag(int4 a, int4 b, short8 &bh, short8 &bl){
  int h0 = (int)(((unsigned)a.x >> 16) | ((unsigned)a.y & 0xFFFF0000u));
  int h1 = (int)(((unsigned)a.z >> 16) | ((unsigned)a.w & 0xFFFF0000u));
  int h2 = (int)(((unsigned)b.x >> 16) | ((unsigned)b.y & 0xFFFF0000u));
  int h3 = (int)(((unsigned)b.z >> 16) | ((unsigned)b.w & 0xFFFF0000u));
  int l0 = (int)(((unsigned)a.x & 0xFFFFu) | ((unsigned)a.y << 16));
  int l1 = (int)(((unsigned)a.z & 0xFFFFu) | ((unsigned)a.w << 16));
  int l2 = (int)(((unsigned)b.x & 0xFFFFu) | ((unsigned)b.y << 16));
  int l3 = (int)(((unsigned)b.z & 0xFFFFu) | ((unsigned)b.w << 16));
  int4 H = make_int4(h0,h1,h2,h3), L = make_int4(l0,l1,l2,l3);
  bh = *(short8*)&H; bl = *(short8*)&L;
}

// ---------- compile-time tables ----------
// Tile = (ring, m-chunk, type=re/im, v-half). Grouped so ALL tiles of a ring
// land on the same XCD (dispatch index == q mod 8 within a group of 8 rings),
// making the ring's x and twiddle slab L2-resident after the first block.
struct TileT { unsigned char ring, mc, type, vh; };
constexpr int nvar_of(int r){
  int mhi=(5+r<128)?(5+r):128;
  int mtn=(mhi+15)/16;
  int nch=(mtn+3)/4;
  return nch*4;                      // mc-chunks x {re,im} x {v0,v1}
}
constexpr int calc_ntiles(){
  int tot=0;
  for(int g=0; g<16; g++){
    int mv=0;
    for(int q=0;q<8;q++){ int nv=nvar_of(127-(g*8+q)); if(nv>mv) mv=nv; }
    tot += 8*mv;
  }
  return tot;
}
constexpr int NTILES = calc_ntiles();          // = 800 (multiple of 8)
struct Tiles { TileT t[NTILES]; };
constexpr Tiles make_tiles(){
  Tiles T{}; int k=0;
  for(int g=0; g<16; g++){                     // heavy rings first
    int mv=0;
    for(int q=0;q<8;q++){ int nv=nvar_of(127-(g*8+q)); if(nv>mv) mv=nv; }
    for(int var=0; var<mv; var++)
      for(int q=0;q<8;q++){
        int r = 127-(g*8+q);
        if(var < nvar_of(r)){
          T.t[k].ring=(unsigned char)r;
          T.t[k].mc  =(unsigned char)(var>>2);
          T.t[k].type=(unsigned char)((var>>1)&1);
          T.t[k].vh  =(unsigned char)(var&1);
        } else {
          T.t[k].ring=255;                     // dummy slot (early exit)
        }
        k++;
      }
  }
  return T;
}
__constant__ Tiles TILES = make_tiles();

struct Offs { long o[129]; };
constexpr Offs make_offs(){
  Offs O{}; long off=0;
  for(int r=0;r<128;r++){
    O.o[r]=off;
    int mh=(5+r<128)?(5+r):128, jc=11+2*r;
    off += 4L*(((mh+15)/16)*16)*(((jc+31)/32)*32);
  }
  O.o[128]=off;
  return O;
}
__constant__ Offs TWOFF = make_offs();
constexpr long TWATOT = make_offs().o[128];

// Padded per-ring twiddle slabs: [cos_hi|cos_lo|sin_hi|sin_lo][Mpad][Kpad] bf16.
__global__ void fill_tw(unsigned short* __restrict__ twA){
  int ring = blockIdx.x, t = blockIdx.y, mq = blockIdx.z;   // m-split x4
  int N = 20+4*ring, H = N/2, JC = H+1;
  int mhi = (5+ring<128)?(5+ring):128;
  int Mpad = ((mhi+15)>>4)<<4;
  int Kpad = ((JC+31)>>5)<<5;
  long MK = (long)Mpad*Kpad;
  unsigned short* hiT = twA + TWOFF.o[ring] + (long)(t*2)*MK;
  unsigned short* loT = hiT + MK;
  float invN = 1.0f/(float)N;
  int tid = threadIdx.x;
  for(int m=mq; m<Mpad; m+=4){
    int p0   = (int)(((long)m*tid) % N);
    int step = (int)(((long)m*256) % N);
    int p = p0;
    for(int j=tid;j<Kpad;j+=256){
      float val = 0.f;
      if(m < mhi && j < JC){
        float th = 6.2831853071795864f * (float)p * invN;
        float sn, cs; __sincosf(th,&sn,&cs);
        val = (t ? -sn : cs) * invN;
      }
      unsigned h = f2bf(val);
      unsigned l = f2bf(val - bf2f(h));
      long idx = (long)m*Kpad + j;
      hiT[idx] = (unsigned short)h;
      loT[idx] = (unsigned short)l;
      p += step; if(p>=N) p-=N;
    }
  }
}

// Folded ragged DFT as split-bf16 MFMA GEMM; tiles XCD-grouped per ring.
__global__ __launch_bounds__(256) void dft_mfma(const float* __restrict__ x,
                                                const unsigned short* __restrict__ twA,
                                                unsigned* __restrict__ Gp){
  TileT tl = TILES.t[blockIdx.x];
  if(tl.ring == 255) return;
  int ring = tl.ring, type = tl.type, vh = tl.vh;
  int b = blockIdx.y;
  int N = 20+4*ring, H = N/2, JC = H+1;
  int mhi = (5+ring<128)?(5+ring):128;
  int MtN = (mhi+15)>>4;
  int Mt0 = tl.mc*4;
  int KT = (JC+31)>>5;
  int Kpad = KT<<5;
  int Mpad = MtN<<4;

  long MK = (long)Mpad*Kpad;
  const unsigned short* Ahi = twA + TWOFF.o[ring] + (long)(type*2)*MK;
  const unsigned short* Alo = Ahi + MK;

  const float* xn = x + ((long)b*NGRID + (long)ring*(2*ring+18))*NV;
  long a1 = ring+1;
  const float* xs = x + ((long)b*NGRID + (NGRID - a1*(2*a1+18)))*NV;

  __shared__ __align__(16) unsigned Bp[4096];   // [c'=128][k=32] u32-packed, swizzled

  int tid = threadIdx.x;
  int jb = tid >> 5;            // 8 j-blocks of 4 rows
  int vp = tid & 31;            // v-pair: v = vh*64 + vp*2 + dv
  int vo = vh*64 + vp*2;
  int wave = tid >> 6, lane = tid & 63;
  int jj = lane & 15, kb = lane >> 4;

  f32x4 acc[4][2];
  #pragma unroll
  for(int Mt=0;Mt<4;Mt++){ acc[Mt][0]=(f32x4){0.f,0.f,0.f,0.f}; acc[Mt][1]=(f32x4){0.f,0.f,0.f,0.f}; }

  for(int kt=0; kt<KT; ++kt){
    __syncthreads();
    // ---- stage fold tile: 4 j-rows x 2 v per thread -> 4 int4 LDS writes ----
    float gSx[4], gSy[4], gAx[4], gAy[4];
    #pragma unroll
    for(int dj=0;dj<4;dj++){
      int j = kt*32 + jb*4 + dj;
      float2 nj=make_float2(0.f,0.f), sj=nj, np=nj, sp=nj;
      if(j < JC){
        nj = *(const float2*)&xn[(long)j*NV + vo];
        sj = *(const float2*)&xs[(long)j*NV + vo];
        if(j > 0 && j < H){
          int jp = N - j;
          np = *(const float2*)&xn[(long)jp*NV + vo];
          sp = *(const float2*)&xs[(long)jp*NV + vo];
        }
      }
      float ex=nj.x+sj.x, ey=nj.y+sj.y, ox=nj.x-sj.x, oy=nj.y-sj.y;
      float epx=np.x+sp.x, epy=np.y+sp.y, opx=np.x-sp.x, opy=np.y-sp.y;
      gSx[dj] = type ? (ex-epx) : (ex+epx);
      gSy[dj] = type ? (ey-epy) : (ey+epy);
      gAx[dj] = type ? (ox-opx) : (ox+opx);
      gAy[dj] = type ? (oy-opy) : (oy+opy);
    }
    {
      int c0 = (vp*2)*2;          // dv=0, par=0 (sym)
      int4 w0 = make_int4((int)packsplit(gSx[0]),(int)packsplit(gSx[1]),
                          (int)packsplit(gSx[2]),(int)packsplit(gSx[3]));
      *(int4*)&Bp[c0*32 + ((jb*4) ^ (swzc(c0)<<2))] = w0;
      int c1 = c0+1;              // dv=0, par=1 (anti)
      int4 w1 = make_int4((int)packsplit(gAx[0]),(int)packsplit(gAx[1]),
                          (int)packsplit(gAx[2]),(int)packsplit(gAx[3]));
      *(int4*)&Bp[c1*32 + ((jb*4) ^ (swzc(c1)<<2))] = w1;
      int c2 = c0+2;              // dv=1, par=0
      int4 w2 = make_int4((int)packsplit(gSy[0]),(int)packsplit(gSy[1]),
                          (int)packsplit(gSy[2]),(int)packsplit(gSy[3]));
      *(int4*)&Bp[c2*32 + ((jb*4) ^ (swzc(c2)<<2))] = w2;
      int c3 = c0+3;              // dv=1, par=1
      int4 w3 = make_int4((int)packsplit(gAy[0]),(int)packsplit(gAy[1]),
                          (int)packsplit(gAy[2]),(int)packsplit(gAy[3]));
      *(int4*)&Bp[c3*32 + ((jb*4) ^ (swzc(c3)<<2))] = w3;
    }
    __syncthreads();
    // ---- B fragments: wave covers cols wave*32..+31 (2 col-tiles) ----
    short8 bh[2], bl[2];
    #pragma unroll
    for(int ct=0;ct<2;ct++){
      int c = wave*32 + ct*16 + jj;
      int sw = swzc(c)<<2;
      int4 pa = *(const int4*)&Bp[c*32 + ((kb*8) ^ sw)];
      int4 pb = *(const int4*)&Bp[c*32 + ((kb*8+4) ^ sw)];
      unpack_frag(pa, pb, bh[ct], bl[ct]);
    }
    // ---- A fragments (global, L2-resident after first block of ring) ----
    #pragma unroll
    for(int Mt=0;Mt<4;Mt++){
      if(Mt0+Mt < MtN){
        long ao = (long)((Mt0+Mt)*16 + jj)*Kpad + kt*32 + kb*8;
        short8 ah = *(const short8*)&Ahi[ao];
        short8 al = *(const short8*)&Alo[ao];
        #pragma unroll
        for(int ct=0;ct<2;ct++){
          acc[Mt][ct] = __builtin_amdgcn_mfma_f32_16x16x32_bf16(ah, bh[ct], acc[Mt][ct], 0,0,0);
          acc[Mt][ct] = __builtin_amdgcn_mfma_f32_16x16x32_bf16(al, bh[ct], acc[Mt][ct], 0,0,0);
          acc[Mt][ct] = __builtin_amdgcn_mfma_f32_16x16x32_bf16(ah, bl[ct], acc[Mt][ct], 0,0,0);
        }
      }
    }
  }
  // ---- epilogue: D col=lane&15, row=kb*4+reg; Gp[s][ri][m][n][b][v] u32 ----
  #pragma unroll
  for(int Mt=0;Mt<4;Mt++){
    if(Mt0+Mt < MtN){
      #pragma unroll
      for(int ct=0;ct<2;ct++){
        int cg = vh*128 + wave*32 + ct*16 + jj;
        int s = cg & 1, v = cg >> 1;
        #pragma unroll
        for(int reg=0;reg<4;reg++){
          int m = (Mt0+Mt)*16 + (kb<<2) + reg;
          if(m < mhi){
            Gp[(long)((s*2+type)*128 + m)*65536 + (long)ring*512 + b*128 + v]
              = packsplit(acc[Mt][ct][reg]);
          }
        }
      }
    }
  }
}

// Split W (fp32) into bf16 hi/lo tables. Layout [s][m][l][n] flat.
__global__ void w_split(const float* __restrict__ Wsym, const float* __restrict__ Want,
                        unsigned short* __restrict__ Wh, unsigned short* __restrict__ Wl){
  long i = (long)blockIdx.x*256 + threadIdx.x;   // 0 .. 2*1048576-1
  const float* W = (i < 1048576) ? Wsym : Want;
  float w = W[i & 1048575];
  unsigned h = f2bf(w);
  unsigned l = f2bf(w - bf2f(h));
  Wh[i] = (unsigned short)h;
  Wl[i] = (unsigned short)l;
}

// Per-(m,b,s) Legendre matmul via split-bf16 MFMA.
__global__ __launch_bounds__(256) void legendre_mfma(const unsigned short* __restrict__ Wh,
                                                     const unsigned short* __restrict__ Wl,
                                                     const unsigned* __restrict__ Gp,
                                                     float* __restrict__ out){
  int m = blockIdx.x, b = blockIdx.y, s = blockIdx.z;
  __shared__ __align__(16) unsigned Bp[8192];   // [c=256][k=32] u32-packed, swizzled
  int tid = threadIdx.x;
  int wave = tid >> 6, lane = tid & 63;
  int jj = lane & 15, kb = lane >> 4;

  int kt0 = (m > 4) ? ((m-4) >> 5) : 0;         // W[m][l][n]==0 for n<m-4

  const unsigned short* WA = Wh + (long)(s*128+m)*8192;   // [l][n] 64x128
  const unsigned short* WB = Wl + (long)(s*128+m)*8192;
  int ri = tid & 1, v = tid >> 1;
  long gC0 = (long)((s*2+ri)*128 + m)*65536 + (long)b*128 + v;  // + n*512

  f32x4 acc[4][4];
  #pragma unroll
  for(int a=0;a<4;a++)
    #pragma unroll
    for(int q=0;q<4;q++) acc[a][q] = (f32x4){0.f,0.f,0.f,0.f};

  int swT = swzc(tid)<<2;
  for(int kt=kt0; kt<4; ++kt){
    __syncthreads();
    #pragma unroll
    for(int k4=0;k4<32;k4+=4){
      int4 w = make_int4((int)Gp[gC0 + (long)(kt*32+k4+0)*512],
                         (int)Gp[gC0 + (long)(kt*32+k4+1)*512],
                         (int)Gp[gC0 + (long)(kt*32+k4+2)*512],
                         (int)Gp[gC0 + (long)(kt*32+k4+3)*512]);
      *(int4*)&Bp[tid*32 + (k4 ^ swT)] = w;
    }
    __syncthreads();
    short8 bh[4], bl[4];
    #pragma unroll
    for(int nt=0;nt<4;nt++){
      int c = (wave*4+nt)*16 + jj;
      int sw = swzc(c)<<2;
      int4 pa = *(const int4*)&Bp[c*32 + ((kb*8) ^ sw)];
      int4 pb = *(const int4*)&Bp[c*32 + ((kb*8+4) ^ sw)];
      unpack_frag(pa, pb, bh[nt], bl[nt]);
    }
    #pragma unroll
    for(int Mt=0;Mt<4;Mt++){
      long ao = (long)(Mt*16 + jj)*128 + kt*32 + kb*8;
      short8 ah = *(const short8*)&WA[ao];
      short8 al = *(const short8*)&WB[ao];
      #pragma unroll
      for(int nt=0;nt<4;nt++){
        acc[Mt][nt] = __builtin_amdgcn_mfma_f32_16x16x32_bf16(ah, bh[nt], acc[Mt][nt], 0,0,0);
        acc[Mt][nt] = __builtin_amdgcn_mfma_f32_16x16x32_bf16(al, bh[nt], acc[Mt][nt], 0,0,0);
        acc[Mt][nt] = __builtin_amdgcn_mfma_f32_16x16x32_bf16(ah, bl[nt], acc[Mt][nt], 0,0,0);
      }
    }
  }
  int r4 = (lane>>4)<<2;
  #pragma unroll
  for(int Mt=0;Mt<4;Mt++){
    #pragma unroll
    for(int nt=0;nt<4;nt++){
      int c = (wave*4+nt)*16 + jj;
      #pragma unroll
      for(int reg=0;reg<4;reg++){
        int l = Mt*16 + r4 + reg;
        out[((long)(b*128 + 2*l + s)*128 + m)*256 + c] = acc[Mt][nt][reg];
      }
    }
  }
}

extern "C" void kernel_launch(void* const* d_in, const int* in_sizes, int n_in,
                              void* d_out, int out_size, void* d_ws, size_t ws_size,
                              hipStream_t stream) {
  const float* x    = (const float*)d_in[0];
  const float* Wsym = (const float*)d_in[1];
  const float* Want = (const float*)d_in[2];
  float* out = (float*)d_out;

  size_t gpOffB = (size_t)TWATOT*2;
  if(gpOffB < 8388608) gpOffB = 8388608;        // keep room for Wh/Wl overlap
  gpOffB = (gpOffB + 255) & ~(size_t)255;

  unsigned short* twA = (unsigned short*)d_ws;
  unsigned* Gp = (unsigned*)((char*)d_ws + gpOffB);     // 134 MB packed G
  unsigned short* Wh = (unsigned short*)d_ws;           // overlaps twA (dead after dft)
  unsigned short* Wl = Wh + 2097152;

  hipLaunchKernelGGL(fill_tw,       dim3(128,2,4),   dim3(256), 0, stream, twA);
  hipLaunchKernelGGL(dft_mfma,      dim3(NTILES,4),  dim3(256), 0, stream, x, twA, Gp);
  hipLaunchKernelGGL(w_split,       dim3(8192),      dim3(256), 0, stream, Wsym, Want, Wh, Wl);
  hipLaunchKernelGGL(legendre_mfma, dim3(128,4,2),   dim3(256), 0, stream, Wh, Wl, Gp, out);
}

// Round 10
// 357.715 us; speedup vs baseline: 1.3650x; 1.0030x over previous
//
#include <hip/hip_runtime.h>
#include <hip/hip_bf16.h>

#define NGRID 70144
#define NV 128

typedef float f32x4 __attribute__((ext_vector_type(4)));
typedef short short8 __attribute__((ext_vector_type(8)));

__device__ __forceinline__ unsigned f2bf(float f){
  return (unsigned)__bfloat16_as_ushort(__float2bfloat16(f));   // RNE
}
__device__ __forceinline__ float bf2f(unsigned h){ return __uint_as_float(h<<16); }
__device__ __forceinline__ unsigned packsplit(float f){
  unsigned h = f2bf(f);
  unsigned l = f2bf(f - bf2f(h));
  return (h<<16) | l;
}
__device__ __forceinline__ int swzc(int c){ return (c ^ (c>>3)) & 7; }

__device__ __forceinline__ void unpack_frag(int4 a, int4 b, short8 &bh, short8 &bl){
  int h0 = (int)(((unsigned)a.x >> 16) | ((unsigned)a.y & 0xFFFF0000u));
  int h1 = (int)(((unsigned)a.z >> 16) | ((unsigned)a.w & 0xFFFF0000u));
  int h2 = (int)(((unsigned)b.x >> 16) | ((unsigned)b.y & 0xFFFF0000u));
  int h3 = (int)(((unsigned)b.z >> 16) | ((unsigned)b.w & 0xFFFF0000u));
  int l0 = (int)(((unsigned)a.x & 0xFFFFu) | ((unsigned)a.y << 16));
  int l1 = (int)(((unsigned)a.z & 0xFFFFu) | ((unsigned)a.w << 16));
  int l2 = (int)(((unsigned)b.x & 0xFFFFu) | ((unsigned)b.y << 16));
  int l3 = (int)(((unsigned)b.z & 0xFFFFu) | ((unsigned)b.w << 16));
  int4 H = make_int4(h0,h1,h2,h3), L = make_int4(l0,l1,l2,l3);
  bh = *(short8*)&H; bl = *(short8*)&L;
}

// ---------- compile-time tables ----------
// Tile = (ring, type=re/im, v-half): 4 uniform variants per ring, full M span.
// XCD-grouped: all variants of a ring at dispatch index == q (mod 8).
struct TileT { unsigned char ring, type, vh; };
constexpr int NTILES = 512;
struct Tiles { TileT t[NTILES]; };
constexpr Tiles make_tiles(){
  Tiles T{}; int k=0;
  for(int g=0; g<16; g++){                     // heavy rings first
    for(int var=0; var<4; var++)
      for(int q=0; q<8; q++){
        int r = 127-(g*8+q);
        T.t[k].ring=(unsigned char)r;
        T.t[k].type=(unsigned char)(var>>1);
        T.t[k].vh  =(unsigned char)(var&1);
        k++;
      }
  }
  return T;
}
__constant__ Tiles TILES = make_tiles();

struct Offs { long o[129]; };
constexpr Offs make_offs(){
  Offs O{}; long off=0;
  for(int r=0;r<128;r++){
    O.o[r]=off;
    int mh=(5+r<128)?(5+r):128, jc=11+2*r;
    off += 4L*(((mh+15)/16)*16)*(((jc+31)/32)*32);
  }
  O.o[128]=off;
  return O;
}
__constant__ Offs TWOFF = make_offs();
constexpr long TWATOT = make_offs().o[128];

// Padded per-ring twiddle slabs: [cos_hi|cos_lo|sin_hi|sin_lo][Mpad][Kpad] bf16.
__global__ void fill_tw(unsigned short* __restrict__ twA){
  int ring = blockIdx.x, t = blockIdx.y, mq = blockIdx.z;   // m-split x4
  int N = 20+4*ring, H = N/2, JC = H+1;
  int mhi = (5+ring<128)?(5+ring):128;
  int Mpad = ((mhi+15)>>4)<<4;
  int Kpad = ((JC+31)>>5)<<5;
  long MK = (long)Mpad*Kpad;
  unsigned short* hiT = twA + TWOFF.o[ring] + (long)(t*2)*MK;
  unsigned short* loT = hiT + MK;
  float invN = 1.0f/(float)N;
  int tid = threadIdx.x;
  for(int m=mq; m<Mpad; m+=4){
    int p0   = (int)(((long)m*tid) % N);
    int step = (int)(((long)m*256) % N);
    int p = p0;
    for(int j=tid;j<Kpad;j+=256){
      float val = 0.f;
      if(m < mhi && j < JC){
        float th = 6.2831853071795864f * (float)p * invN;
        float sn, cs; __sincosf(th,&sn,&cs);
        val = (t ? -sn : cs) * invN;
      }
      unsigned h = f2bf(val);
      unsigned l = f2bf(val - bf2f(h));
      long idx = (long)m*Kpad + j;
      hiT[idx] = (unsigned short)h;
      loT[idx] = (unsigned short)l;
      p += step; if(p>=N) p-=N;
    }
  }
}

// Folded ragged DFT as split-bf16 MFMA GEMM; full-M blocks, x prefetch (T14),
// tiles XCD-grouped per ring.
__global__ __launch_bounds__(256,3) void dft_mfma(const float* __restrict__ x,
                                                  const unsigned short* __restrict__ twA,
                                                  unsigned* __restrict__ Gp){
  TileT tl = TILES.t[blockIdx.x];
  int ring = tl.ring, type = tl.type, vh = tl.vh;
  int b = blockIdx.y;
  int N = 20+4*ring, H = N/2, JC = H+1;
  int mhi = (5+ring<128)?(5+ring):128;
  int MtN = (mhi+15)>>4;
  int KT = (JC+31)>>5;
  int Kpad = KT<<5;
  int Mpad = MtN<<4;

  long MK = (long)Mpad*Kpad;
  const unsigned short* Ahi = twA + TWOFF.o[ring] + (long)(type*2)*MK;
  const unsigned short* Alo = Ahi + MK;

  const float* xn = x + ((long)b*NGRID + (long)ring*(2*ring+18))*NV;
  long a1 = ring+1;
  const float* xs = x + ((long)b*NGRID + (NGRID - a1*(2*a1+18)))*NV;

  __shared__ __align__(16) unsigned Bp[4096];   // [c'=128][k=32] u32-packed, swizzled

  int tid = threadIdx.x;
  int jb = tid >> 5;            // 8 j-blocks of 4 rows
  int vp = tid & 31;            // v-pair: v = vh*64 + vp*2 + dv
  int vo = vh*64 + vp*2;
  int wave = tid >> 6, lane = tid & 63;
  int jj = lane & 15, kb = lane >> 4;

  f32x4 acc[8][2];
  #pragma unroll
  for(int Mt=0;Mt<8;Mt++){ acc[Mt][0]=(f32x4){0.f,0.f,0.f,0.f}; acc[Mt][1]=(f32x4){0.f,0.f,0.f,0.f}; }

  // x prefetch buffer: 16 float2 (32 VGPR)
  float2 rn[4], rs[4], rpn[4], rps[4];
  #define LOADX(KT_)                                              \
  {                                                               \
    int ktl = (KT_);                                              \
    _Pragma("unroll")                                             \
    for(int dj=0;dj<4;dj++){                                      \
      int j = ktl*32 + jb*4 + dj;                                 \
      float2 zz = make_float2(0.f,0.f);                           \
      rn[dj]=zz; rs[dj]=zz; rpn[dj]=zz; rps[dj]=zz;               \
      if(j < JC){                                                 \
        rn[dj] = *(const float2*)&xn[(long)j*NV + vo];            \
        rs[dj] = *(const float2*)&xs[(long)j*NV + vo];            \
        if(j > 0 && j < H){                                       \
          int jp = N - j;                                         \
          rpn[dj] = *(const float2*)&xn[(long)jp*NV + vo];        \
          rps[dj] = *(const float2*)&xs[(long)jp*NV + vo];        \
        }                                                         \
      }                                                           \
    }                                                             \
  }

  LOADX(0);
  for(int kt=0; kt<KT; ++kt){
    // ---- fold + pack from prefetched regs ----
    int4 w0, w1, w2, w3;
    {
      float sx[4], sy[4], ax[4], ay[4];
      #pragma unroll
      for(int dj=0;dj<4;dj++){
        float ex=rn[dj].x+rs[dj].x, ey=rn[dj].y+rs[dj].y;
        float ox=rn[dj].x-rs[dj].x, oy=rn[dj].y-rs[dj].y;
        float epx=rpn[dj].x+rps[dj].x, epy=rpn[dj].y+rps[dj].y;
        float opx=rpn[dj].x-rps[dj].x, opy=rpn[dj].y-rps[dj].y;
        sx[dj] = type ? (ex-epx) : (ex+epx);
        sy[dj] = type ? (ey-epy) : (ey+epy);
        ax[dj] = type ? (ox-opx) : (ox+opx);
        ay[dj] = type ? (oy-opy) : (oy+opy);
      }
      w0 = make_int4((int)packsplit(sx[0]),(int)packsplit(sx[1]),
                     (int)packsplit(sx[2]),(int)packsplit(sx[3]));
      w1 = make_int4((int)packsplit(ax[0]),(int)packsplit(ax[1]),
                     (int)packsplit(ax[2]),(int)packsplit(ax[3]));
      w2 = make_int4((int)packsplit(sy[0]),(int)packsplit(sy[1]),
                     (int)packsplit(sy[2]),(int)packsplit(sy[3]));
      w3 = make_int4((int)packsplit(ay[0]),(int)packsplit(ay[1]),
                     (int)packsplit(ay[2]),(int)packsplit(ay[3]));
    }
    __syncthreads();                 // prior kt's frag reads complete
    {
      int c0 = vp*4;                 // (dv,par) = (0,0),(0,1),(1,0),(1,1)
      *(int4*)&Bp[(c0+0)*32 + ((jb*4) ^ (swzc(c0+0)<<2))] = w0;
      *(int4*)&Bp[(c0+1)*32 + ((jb*4) ^ (swzc(c0+1)<<2))] = w1;
      *(int4*)&Bp[(c0+2)*32 + ((jb*4) ^ (swzc(c0+2)<<2))] = w2;
      *(int4*)&Bp[(c0+3)*32 + ((jb*4) ^ (swzc(c0+3)<<2))] = w3;
    }
    __syncthreads();                 // writes visible
    if(kt+1 < KT) LOADX(kt+1);       // T14: issue next tile's loads now
    // ---- B fragments: wave covers cols wave*32..+31 (2 col-tiles) ----
    short8 bh[2], bl[2];
    #pragma unroll
    for(int ct=0;ct<2;ct++){
      int c = wave*32 + ct*16 + jj;
      int sw = swzc(c)<<2;
      int4 pa = *(const int4*)&Bp[c*32 + ((kb*8) ^ sw)];
      int4 pb = *(const int4*)&Bp[c*32 + ((kb*8+4) ^ sw)];
      unpack_frag(pa, pb, bh[ct], bl[ct]);
    }
    // ---- A fragments (global, L2-resident) + MFMA over full M ----
    #pragma unroll
    for(int Mt=0;Mt<8;Mt++){
      if(Mt < MtN){
        long ao = (long)(Mt*16 + jj)*Kpad + kt*32 + kb*8;
        short8 ah = *(const short8*)&Ahi[ao];
        short8 al = *(const short8*)&Alo[ao];
        #pragma unroll
        for(int ct=0;ct<2;ct++){
          acc[Mt][ct] = __builtin_amdgcn_mfma_f32_16x16x32_bf16(ah, bh[ct], acc[Mt][ct], 0,0,0);
          acc[Mt][ct] = __builtin_amdgcn_mfma_f32_16x16x32_bf16(al, bh[ct], acc[Mt][ct], 0,0,0);
          acc[Mt][ct] = __builtin_amdgcn_mfma_f32_16x16x32_bf16(ah, bl[ct], acc[Mt][ct], 0,0,0);
        }
      }
    }
  }
  // ---- epilogue: D col=lane&15, row=kb*4+reg; Gp[s][ri][m][n][b][v] u32 ----
  #pragma unroll
  for(int Mt=0;Mt<8;Mt++){
    if(Mt < MtN){
      #pragma unroll
      for(int ct=0;ct<2;ct++){
        int cg = vh*128 + wave*32 + ct*16 + jj;
        int s = cg & 1, v = cg >> 1;
        #pragma unroll
        for(int reg=0;reg<4;reg++){
          int m = Mt*16 + (kb<<2) + reg;
          if(m < mhi){
            Gp[(long)((s*2+type)*128 + m)*65536 + (long)ring*512 + b*128 + v]
              = packsplit(acc[Mt][ct][reg]);
          }
        }
      }
    }
  }
  #undef LOADX
}

// Split W (fp32) into bf16 hi/lo tables. Layout [s][m][l][n] flat.
__global__ void w_split(const float* __restrict__ Wsym, const float* __restrict__ Want,
                        unsigned short* __restrict__ Wh, unsigned short* __restrict__ Wl){
  long i = (long)blockIdx.x*256 + threadIdx.x;   // 0 .. 2*1048576-1
  const float* W = (i < 1048576) ? Wsym : Want;
  float w = W[i & 1048575];
  unsigned h = f2bf(w);
  unsigned l = f2bf(w - bf2f(h));
  Wh[i] = (unsigned short)h;
  Wl[i] = (unsigned short)l;
}

// Per-(m,b,s) Legendre matmul via split-bf16 MFMA.
__global__ __launch_bounds__(256) void legendre_mfma(const unsigned short* __restrict__ Wh,
                                                     const unsigned short* __restrict__ Wl,
                                                     const unsigned* __restrict__ Gp,
                                                     float* __restrict__ out){
  int m = blockIdx.x, b = blockIdx.y, s = blockIdx.z;
  __shared__ __align__(16) unsigned Bp[8192];   // [c=256][k=32] u32-packed, swizzled
  int tid = threadIdx.x;
  int wave = tid >> 6, lane = tid & 63;
  int jj = lane & 15, kb = lane >> 4;

  int kt0 = (m > 4) ? ((m-4) >> 5) : 0;         // W[m][l][n]==0 for n<m-4

  const unsigned short* WA = Wh + (long)(s*128+m)*8192;   // [l][n] 64x128
  const unsigned short* WB = Wl + (long)(s*128+m)*8192;
  int ri = tid & 1, v = tid >> 1;
  long gC0 = (long)((s*2+ri)*128 + m)*65536 + (long)b*128 + v;  // + n*512

  f32x4 acc[4][4];
  #pragma unroll
  for(int a=0;a<4;a++)
    #pragma unroll
    for(int q=0;q<4;q++) acc[a][q] = (f32x4){0.f,0.f,0.f,0.f};

  int swT = swzc(tid)<<2;
  for(int kt=kt0; kt<4; ++kt){
    __syncthreads();
    #pragma unroll
    for(int k4=0;k4<32;k4+=4){
      int4 w = make_int4((int)Gp[gC0 + (long)(kt*32+k4+0)*512],
                         (int)Gp[gC0 + (long)(kt*32+k4+1)*512],
                         (int)Gp[gC0 + (long)(kt*32+k4+2)*512],
                         (int)Gp[gC0 + (long)(kt*32+k4+3)*512]);
      *(int4*)&Bp[tid*32 + (k4 ^ swT)] = w;
    }
    __syncthreads();
    short8 bh[4], bl[4];
    #pragma unroll
    for(int nt=0;nt<4;nt++){
      int c = (wave*4+nt)*16 + jj;
      int sw = swzc(c)<<2;
      int4 pa = *(const int4*)&Bp[c*32 + ((kb*8) ^ sw)];
      int4 pb = *(const int4*)&Bp[c*32 + ((kb*8+4) ^ sw)];
      unpack_frag(pa, pb, bh[nt], bl[nt]);
    }
    #pragma unroll
    for(int Mt=0;Mt<4;Mt++){
      long ao = (long)(Mt*16 + jj)*128 + kt*32 + kb*8;
      short8 ah = *(const short8*)&WA[ao];
      short8 al = *(const short8*)&WB[ao];
      #pragma unroll
      for(int nt=0;nt<4;nt++){
        acc[Mt][nt] = __builtin_amdgcn_mfma_f32_16x16x32_bf16(ah, bh[nt], acc[Mt][nt], 0,0,0);
        acc[Mt][nt] = __builtin_amdgcn_mfma_f32_16x16x32_bf16(al, bh[nt], acc[Mt][nt], 0,0,0);
        acc[Mt][nt] = __builtin_amdgcn_mfma_f32_16x16x32_bf16(ah, bl[nt], acc[Mt][nt], 0,0,0);
      }
    }
  }
  int r4 = (lane>>4)<<2;
  #pragma unroll
  for(int Mt=0;Mt<4;Mt++){
    #pragma unroll
    for(int nt=0;nt<4;nt++){
      int c = (wave*4+nt)*16 + jj;
      #pragma unroll
      for(int reg=0;reg<4;reg++){
        int l = Mt*16 + r4 + reg;
        out[((long)(b*128 + 2*l + s)*128 + m)*256 + c] = acc[Mt][nt][reg];
      }
    }
  }
}

extern "C" void kernel_launch(void* const* d_in, const int* in_sizes, int n_in,
                              void* d_out, int out_size, void* d_ws, size_t ws_size,
                              hipStream_t stream) {
  const float* x    = (const float*)d_in[0];
  const float* Wsym = (const float*)d_in[1];
  const float* Want = (const float*)d_in[2];
  float* out = (float*)d_out;

  size_t gpOffB = (size_t)TWATOT*2;
  if(gpOffB < 8388608) gpOffB = 8388608;        // keep room for Wh/Wl overlap
  gpOffB = (gpOffB + 255) & ~(size_t)255;

  unsigned short* twA = (unsigned short*)d_ws;
  unsigned* Gp = (unsigned*)((char*)d_ws + gpOffB);     // 134 MB packed G
  unsigned short* Wh = (unsigned short*)d_ws;           // overlaps twA (dead after dft)
  unsigned short* Wl = Wh + 2097152;

  hipLaunchKernelGGL(fill_tw,       dim3(128,2,4),   dim3(256), 0, stream, twA);
  hipLaunchKernelGGL(dft_mfma,      dim3(NTILES,4),  dim3(256), 0, stream, x, twA, Gp);
  hipLaunchKernelGGL(w_split,       dim3(8192),      dim3(256), 0, stream, Wsym, Want, Wh, Wl);
  hipLaunchKernelGGL(legendre_mfma, dim3(128,4,2),   dim3(256), 0, stream, Wh, Wl, Gp, out);
}